// Round 5
// baseline (7953.838 us; speedup 1.0000x reference)
//
#include <hip/hip_runtime.h>

#define N 307
#define CIN 5
#define HID 16
#define KORD 6
#define LH 32
#define BATCH 512
#define NP 324          // padded node stride, float4-aligned; zero-padded tail
#define NITEM (BATCH * N)   // 157184; x4 lanes = 628736 = 2456 * 256 exactly

__device__ __forceinline__ float sigmoidf(float x) {
    return __fdividef(1.f, 1.f + __expf(-x));
}
__device__ __forceinline__ float ftanh(float x) {
    float e = __expf(2.f * x);
    return 1.f - __fdividef(2.f, e + 1.f);
}

// ---------------- setup: U^T [10][NP] (L = I - U U^T), zero-padded; LSTM transposes ----------------
__global__ __launch_bounds__(320) void k_setup(const float* __restrict__ E,
                                               const float* __restrict__ Wih,
                                               float* __restrict__ Ut,
                                               float* __restrict__ WiT,
                                               float* __restrict__ WgT,
                                               float* __restrict__ WoT) {
    __shared__ float EnS[N * 10];
    __shared__ float sS[10];
    __shared__ float dS[N];
    const int t = threadIdx.x;
    if (t < N) {
        float v[10]; float nrm = 0.f;
        #pragma unroll
        for (int p = 0; p < 10; p++) { v[p] = E[t * 10 + p]; nrm = fmaf(v[p], v[p], nrm); }
        float r = rsqrtf(nrm);
        #pragma unroll
        for (int p = 0; p < 10; p++) EnS[t * 10 + p] = v[p] * r;
    }
    __syncthreads();
    if (t < 10) {
        float s = 0.f;
        for (int nn = 0; nn < N; nn++) s += EnS[nn * 10 + t];
        sS[t] = s;
    }
    __syncthreads();
    if (t < N) {
        float dot = 0.f;
        #pragma unroll
        for (int p = 0; p < 10; p++) dot = fmaf(EnS[t * 10 + p], sS[p], dot);
        dS[t] = rsqrtf(dot);
    }
    __syncthreads();
    for (int i = t; i < 10 * NP; i += 320) {
        int p = i / NP, nn = i - p * NP;
        Ut[i] = (nn < N) ? dS[nn] * EnS[nn * 10 + p] : 0.f;
    }
    for (int i = t; i < LH * HID; i += 320) {
        int j = i >> 4, h = i & 15;
        WiT[i] = Wih[h * 4 * LH + j];
        WgT[i] = Wih[h * 4 * LH + 2 * LH + j];
        WoT[i] = Wih[h * 4 * LH + 3 * LH + j];
    }
}

// ---------------- S[p*5+c] = sum_n U[n,p]*X[n,c]; 6 segments of 52 ----------------
__device__ __forceinline__ void reduce5(const float* __restrict__ Ub,
                                        const float* __restrict__ Xb,
                                        float* __restrict__ Sp,
                                        float* __restrict__ Sb, int t) {
    const int o = t % 50, sg = t / 50;
    if (sg < 6) {
        const int p = o / 5, c = o - (o / 5) * 5;
        int n0 = sg * 52, n1 = n0 + 52; if (n1 > N) n1 = N;
        const float* up = Ub + p * NP;
        const float* xp = Xb + c * NP;
        float acc = 0.f;
        #pragma unroll 4
        for (int nn = n0; nn < n1; nn++) acc = fmaf(up[nn], xp[nn], acc);
        Sp[t] = acc;
    }
    __syncthreads();
    if (t < 50) {
        float s = 0.f;
        #pragma unroll
        for (int sgi = 0; sgi < 6; sgi++) s += Sp[t + 50 * sgi];
        Sb[t] = s;
    }
    __syncthreads();
}

// ---------------- S[p*16+h] = sum_n U[n,p]*V[n,h]; float4, 2 segments of 160 ----------------
__device__ __forceinline__ void reduce16(const float* __restrict__ Ub,
                                         const float* __restrict__ Vb,
                                         float* __restrict__ Sp,
                                         float* __restrict__ Sb, int t) {
    const int o = t % 160, sg = t / 160;     // sg in {0,1}
    const int p = o >> 4, c = o & 15;
    const float4* up = (const float4*)(Ub + p * NP + sg * 160);
    const float4* xp = (const float4*)(Vb + c * NP + sg * 160);
    float a0 = 0.f, a1 = 0.f;
    #pragma unroll 8
    for (int q = 0; q < 40; q += 2) {
        float4 u0 = up[q], x0 = xp[q];
        a0 = fmaf(u0.x, x0.x, a0); a0 = fmaf(u0.y, x0.y, a0);
        a0 = fmaf(u0.z, x0.z, a0); a0 = fmaf(u0.w, x0.w, a0);
        float4 u1 = up[q + 1], x1 = xp[q + 1];
        a1 = fmaf(u1.x, x1.x, a1); a1 = fmaf(u1.y, x1.y, a1);
        a1 = fmaf(u1.z, x1.z, a1); a1 = fmaf(u1.w, x1.w, a1);
    }
    Sp[t] = a0 + a1;
    __syncthreads();
    if (t < 160) Sb[t] = Sp[t] + Sp[t + 160];
    __syncthreads();
}

// ---------------- GL core: z = GL(v), full-width, Sb via broadcast reads ----------------
__device__ __forceinline__ void glcore(const float* __restrict__ v,
                                       const float* __restrict__ U,
                                       const float* __restrict__ Sb,
                                       const float* __restrict__ wo,
                                       const float* __restrict__ wf,
                                       const float* __restrict__ wt,
                                       const float* __restrict__ bt,
                                       float* __restrict__ z) {
    float o1[HID];
    #pragma unroll
    for (int h = 0; h < HID; h++) o1[h] = v[h];
    #pragma unroll
    for (int p = 0; p < 10; p++) {
        float u = U[p];
        const float4* srow = (const float4*)(Sb + p * HID);
        float4 s0 = srow[0], s1 = srow[1], s2 = srow[2], s3 = srow[3];
        o1[0]  = fmaf(-u, s0.x, o1[0]);  o1[1]  = fmaf(-u, s0.y, o1[1]);
        o1[2]  = fmaf(-u, s0.z, o1[2]);  o1[3]  = fmaf(-u, s0.w, o1[3]);
        o1[4]  = fmaf(-u, s1.x, o1[4]);  o1[5]  = fmaf(-u, s1.y, o1[5]);
        o1[6]  = fmaf(-u, s1.z, o1[6]);  o1[7]  = fmaf(-u, s1.w, o1[7]);
        o1[8]  = fmaf(-u, s2.x, o1[8]);  o1[9]  = fmaf(-u, s2.y, o1[9]);
        o1[10] = fmaf(-u, s2.z, o1[10]); o1[11] = fmaf(-u, s2.w, o1[11]);
        o1[12] = fmaf(-u, s3.x, o1[12]); o1[13] = fmaf(-u, s3.y, o1[13]);
        o1[14] = fmaf(-u, s3.z, o1[14]); o1[15] = fmaf(-u, s3.w, o1[15]);
    }
    float y[HID] = {};
    #pragma unroll
    for (int h2 = 0; h2 < HID; h2++) {
        float xv = v[h2];
        #pragma unroll
        for (int h = 0; h < HID; h++) y[h] = fmaf(xv, wo[h2 * HID + h], y[h]);
    }
    #pragma unroll
    for (int h = 0; h < HID; h++) y[h] = ftanh(y[h]);
    float y2[HID] = {};
    #pragma unroll
    for (int h2 = 0; h2 < HID; h2++) {
        float xv = y[h2];
        #pragma unroll
        for (int h = 0; h < HID; h++) y2[h] = fmaf(xv, wf[h2 * HID + h], y2[h]);
    }
    #pragma unroll
    for (int h = 0; h < HID; h++) z[h] = bt[h];
    #pragma unroll
    for (int h2 = 0; h2 < HID; h2++) {
        float vv = o1[h2] - ftanh(y2[h2]);
        #pragma unroll
        for (int h = 0; h < HID; h++) z[h] = fmaf(vv, wt[h2 * HID + h], z[h]);
    }
}

// ---------------- kernel 1: init + cheb + 10x GL + cstep; writes s00/s11/step1 into out ----------------
__global__ __launch_bounds__(320, 3) void k_gl(
    const float* __restrict__ flow, const float* __restrict__ Ut,
    const float* __restrict__ cheb_w, const float* __restrict__ cheb_b,
    const float* __restrict__ cou_w,
    const float* __restrict__ gl_wo, const float* __restrict__ gl_wf,
    const float* __restrict__ gl_wt, const float* __restrict__ gl_bt,
    const float* __restrict__ c_w, const float* __restrict__ c_b,
    const float* __restrict__ c1_w, const float* __restrict__ c1_b,
    float* __restrict__ out) {
    __shared__ __align__(16) float Ub[10 * NP];
    __shared__ __align__(16) float Vb[HID * NP];
    __shared__ __align__(16) float Sp[320];
    __shared__ __align__(16) float Sb[10 * HID];
    const int t = threadIdx.x, b = blockIdx.x;
    const bool act = t < N;

    for (int i = t; i < 10 * NP; i += 320) Ub[i] = Ut[i];
    for (int i = t; i < HID * NP; i += 320) Vb[i] = 0.f;   // pad stays 0 forever
    __syncthreads();
    for (int i = t; i < N * CIN; i += 320) {
        int nn = i / CIN, c = i - nn * CIN;
        Vb[c * NP + nn] = flow[(size_t)b * N * CIN + i];
    }
    __syncthreads();

    float U[10], prev2[HID], cur[HID], tk0[CIN], tk1[CIN];
    if (act) {
        #pragma unroll
        for (int p = 0; p < 10; p++) U[p] = Ub[p * NP + t];
        float xv[CIN];
        #pragma unroll
        for (int c = 0; c < CIN; c++) { xv[c] = Vb[c * NP + t]; tk0[c] = xv[c]; }
        #pragma unroll
        for (int h = 0; h < HID; h++) {
            float s = 0.f, s2 = cheb_b[h];
            #pragma unroll
            for (int c = 0; c < CIN; c++) {
                s = fmaf(xv[c], cou_w[c * HID + h], s);
                s2 = fmaf(xv[c], cheb_w[c * HID + h], s2);   // k=0: T0@x = x
            }
            prev2[h] = s;
            cur[h] = s2;
        }
    }
    reduce5(Ub, Vb, Sp, Sb, t);
    if (act) {
        #pragma unroll
        for (int c = 0; c < CIN; c++) {
            float s = tk0[c];
            #pragma unroll
            for (int p = 0; p < 10; p++) s = fmaf(-U[p], Sb[p * CIN + c], s);
            tk1[c] = s;
        }
        #pragma unroll
        for (int c = 0; c < CIN; c++) {
            float v = tk1[c];
            #pragma unroll
            for (int h = 0; h < HID; h++)
                cur[h] = fmaf(v, cheb_w[CIN * HID + c * HID + h], cur[h]);
        }
    }
    for (int k = 2; k < KORD; k++) {
        if (act) {
            #pragma unroll
            for (int c = 0; c < CIN; c++) Vb[c * NP + t] = tk1[c];
        }
        __syncthreads();
        reduce5(Ub, Vb, Sp, Sb, t);
        if (act) {
            #pragma unroll
            for (int c = 0; c < CIN; c++) {
                float lt = tk1[c];
                #pragma unroll
                for (int p = 0; p < 10; p++) lt = fmaf(-U[p], Sb[p * CIN + c], lt);
                float tn = 2.f * lt - tk0[c];
                tk0[c] = tk1[c];
                tk1[c] = tn;
            }
            #pragma unroll
            for (int c = 0; c < CIN; c++) {
                float v = tk1[c];
                #pragma unroll
                for (int h = 0; h < HID; h++)
                    cur[h] = fmaf(v, cheb_w[(k * CIN + c) * HID + h], cur[h]);
            }
        }
    }

    // ---- GL chain: 10 iters x 2 evals; 3 barriers per eval ----
    for (int it = 0; it < 10; it++) {
        if (act) {
            #pragma unroll
            for (int h = 0; h < HID; h++) Vb[h * NP + t] = cur[h];
        }
        __syncthreads();
        reduce16(Ub, Vb, Sp, Sb, t);
        float tt[HID], wv[HID];
        if (act) {
            glcore(cur, U, Sb, gl_wo, gl_wf, gl_wt, gl_bt, tt);
            #pragma unroll
            for (int h = 0; h < HID; h++) wv[h] = fmaf(2.f, tt[h], prev2[h]);
            #pragma unroll
            for (int h = 0; h < HID; h++) Vb[h * NP + t] = wv[h];
        }
        __syncthreads();
        reduce16(Ub, Vb, Sp, Sb, t);
        if (act) {
            float uu[HID];
            glcore(wv, U, Sb, gl_wo, gl_wf, gl_wt, gl_bt, uu);
            #pragma unroll
            for (int h = 0; h < HID; h++) {
                float nc = cur[h] + 0.5f * (tt[h] + uu[h]);
                prev2[h] = cur[h];
                cur[h] = nc;
            }
        }
    }

    // ---- cstep; stash s00/s11/step1 in out slots 0/1/2 (k_nl overwrites) ----
    if (act) {
        float s00[HID], s11[HID];
        #pragma unroll
        for (int h = 0; h < HID; h++) { s00[h] = c_b[h]; s11[h] = c1_b[h]; }
        #pragma unroll
        for (int h2 = 0; h2 < HID; h2++) {
            float a = prev2[h2], c2v = cur[h2];
            #pragma unroll
            for (int h = 0; h < HID; h++) {
                s00[h] = fmaf(a, c_w[h2 * HID + h], s00[h]);
                s11[h] = fmaf(c2v, c1_w[h2 * HID + h], s11[h]);
            }
        }
        float* ob = out + (size_t)(b * N + t) * 160;
        float4* wq = (float4*)ob;
        wq[0] = make_float4(s00[0], s00[1], s00[2], s00[3]);
        wq[1] = make_float4(s00[4], s00[5], s00[6], s00[7]);
        wq[2] = make_float4(s00[8], s00[9], s00[10], s00[11]);
        wq[3] = make_float4(s00[12], s00[13], s00[14], s00[15]);
        wq[4] = make_float4(s11[0], s11[1], s11[2], s11[3]);
        wq[5] = make_float4(s11[4], s11[5], s11[6], s11[7]);
        wq[6] = make_float4(s11[8], s11[9], s11[10], s11[11]);
        wq[7] = make_float4(s11[12], s11[13], s11[14], s11[15]);
        wq[8] = make_float4(cur[0], cur[1], cur[2], cur[3]);
        wq[9] = make_float4(cur[4], cur[5], cur[6], cur[7]);
        wq[10] = make_float4(cur[8], cur[9], cur[10], cur[11]);
        wq[11] = make_float4(cur[12], cur[13], cur[14], cur[15]);
    }
}

// ---------------- NL quarter-eval: 8 of 32 LSTM rows per lane + quad combine ----------------
__device__ __forceinline__ void nl_eval_q(const float* __restrict__ x,
                                          const float* __restrict__ wi,
                                          const float* __restrict__ wg,
                                          const float* __restrict__ wo,
                                          const float* __restrict__ w2s,
                                          const float* __restrict__ bi_,
                                          const float* __restrict__ bg_,
                                          const float* __restrict__ bo_,
                                          float* __restrict__ outv) {
    float part[HID];
    #pragma unroll
    for (int h = 0; h < HID; h++) part[h] = 0.f;
    #pragma unroll
    for (int jj = 0; jj < 8; jj++) {
        float gi = bi_[jj], gg = bg_[jj], go = bo_[jj];
        const float4* wiq = (const float4*)(wi + jj * HID);
        const float4* wgq = (const float4*)(wg + jj * HID);
        const float4* woq = (const float4*)(wo + jj * HID);
        #pragma unroll
        for (int q = 0; q < 4; q++) {
            float4 a = wiq[q], bb = wgq[q], cc = woq[q];
            gi = fmaf(x[4 * q + 0], a.x, gi); gi = fmaf(x[4 * q + 1], a.y, gi);
            gi = fmaf(x[4 * q + 2], a.z, gi); gi = fmaf(x[4 * q + 3], a.w, gi);
            gg = fmaf(x[4 * q + 0], bb.x, gg); gg = fmaf(x[4 * q + 1], bb.y, gg);
            gg = fmaf(x[4 * q + 2], bb.z, gg); gg = fmaf(x[4 * q + 3], bb.w, gg);
            go = fmaf(x[4 * q + 0], cc.x, go); go = fmaf(x[4 * q + 1], cc.y, go);
            go = fmaf(x[4 * q + 2], cc.z, go); go = fmaf(x[4 * q + 3], cc.w, go);
        }
        float c = sigmoidf(gi) * ftanh(gg);
        float hh = sigmoidf(go) * ftanh(c);
        float th = ftanh(hh);
        const float4* w2q = (const float4*)(w2s + jj * HID);
        #pragma unroll
        for (int q = 0; q < 4; q++) {
            float4 a = w2q[q];
            part[4 * q + 0] = fmaf(th, a.x, part[4 * q + 0]);
            part[4 * q + 1] = fmaf(th, a.y, part[4 * q + 1]);
            part[4 * q + 2] = fmaf(th, a.z, part[4 * q + 2]);
            part[4 * q + 3] = fmaf(th, a.w, part[4 * q + 3]);
        }
    }
    // quad combine: lanes {4k..4k+3} sum their partials; all get the full result
    #pragma unroll
    for (int h = 0; h < HID; h++) {
        float v = part[h];
        v += __shfl_xor(v, 1);
        v += __shfl_xor(v, 2);
        outv[h] = v;
    }
}

// ---------------- kernel 2: NL chain, 4 lanes/item; no LDS, no barriers ----------------
__global__ __launch_bounds__(256, 8) void k_nl(
    const float* __restrict__ WiT, const float* __restrict__ WgT,
    const float* __restrict__ WoT, const float* __restrict__ bih,
    const float* __restrict__ w2, float* __restrict__ out) {
    const int gt = blockIdx.x * 256 + threadIdx.x;
    const int item = gt >> 2, sub = gt & 3;
    if (item >= NITEM) return;
    float* ob = out + (size_t)item * 160;

    const int j0 = sub * 8;
    const float* wi = WiT + j0 * HID;
    const float* wg = WgT + j0 * HID;
    const float* wo = WoT + j0 * HID;
    const float* w2s = w2 + j0 * HID;
    float bi_[8], bg_[8], bo_[8];
    #pragma unroll
    for (int jj = 0; jj < 8; jj++) {
        bi_[jj] = bih[j0 + jj];
        bg_[jj] = bih[2 * LH + j0 + jj];
        bo_[jj] = bih[3 * LH + j0 + jj];
    }

    float s00[HID], s11[HID], curf[HID];
    {
        const float4* rq = (const float4*)ob;
        float4 a0 = rq[0], a1 = rq[1], a2 = rq[2], a3 = rq[3];
        float4 b0 = rq[4], b1 = rq[5], b2 = rq[6], b3 = rq[7];
        float4 c0 = rq[8], c1 = rq[9], c2 = rq[10], c3 = rq[11];
        s00[0] = a0.x; s00[1] = a0.y; s00[2] = a0.z; s00[3] = a0.w;
        s00[4] = a1.x; s00[5] = a1.y; s00[6] = a1.z; s00[7] = a1.w;
        s00[8] = a2.x; s00[9] = a2.y; s00[10] = a2.z; s00[11] = a2.w;
        s00[12] = a3.x; s00[13] = a3.y; s00[14] = a3.z; s00[15] = a3.w;
        s11[0] = b0.x; s11[1] = b0.y; s11[2] = b0.z; s11[3] = b0.w;
        s11[4] = b1.x; s11[5] = b1.y; s11[6] = b1.z; s11[7] = b1.w;
        s11[8] = b2.x; s11[9] = b2.y; s11[10] = b2.z; s11[11] = b2.w;
        s11[12] = b3.x; s11[13] = b3.y; s11[14] = b3.z; s11[15] = b3.w;
        curf[0] = c0.x; curf[1] = c0.y; curf[2] = c0.z; curf[3] = c0.w;
        curf[4] = c1.x; curf[5] = c1.y; curf[6] = c1.z; curf[7] = c1.w;
        curf[8] = c2.x; curf[9] = c2.y; curf[10] = c2.z; curf[11] = c2.w;
        curf[12] = c3.x; curf[13] = c3.y; curf[14] = c3.z; curf[15] = c3.w;
    }

    float tt[HID], uu[HID], g[HID], p2[HID];
    nl_eval_q(s11, wi, wg, wo, w2s, bi_, bg_, bo_, tt);
    #pragma unroll
    for (int h = 0; h < HID; h++) s00[h] = fmaf(2.f, tt[h], s00[h]);
    nl_eval_q(s00, wi, wg, wo, w2s, bi_, bg_, bo_, uu);
    #pragma unroll
    for (int h = 0; h < HID; h++) {
        g[h] = curf[h] + 0.5f * (tt[h] + uu[h]);
        p2[h] = s11[h];
    }
    if (sub == 0) {
        float4* wq = (float4*)ob;
        wq[0] = make_float4(g[0], g[1], g[2], g[3]);
        wq[1] = make_float4(g[4], g[5], g[6], g[7]);
        wq[2] = make_float4(g[8], g[9], g[10], g[11]);
        wq[3] = make_float4(g[12], g[13], g[14], g[15]);
    }
    for (int i = 1; i < 10; i++) {
        nl_eval_q(g, wi, wg, wo, w2s, bi_, bg_, bo_, tt);
        #pragma unroll
        for (int h = 0; h < HID; h++) p2[h] = fmaf(2.f, tt[h], p2[h]);   // p2 := tmp
        nl_eval_q(p2, wi, wg, wo, w2s, bi_, bg_, bo_, uu);
        #pragma unroll
        for (int h = 0; h < HID; h++) {
            float ng = g[h] + 0.5f * (tt[h] + uu[h]);
            p2[h] = g[h];
            g[h] = ng;
        }
        if (sub == 0) {
            float4* wq = (float4*)(ob + i * HID);
            wq[0] = make_float4(g[0], g[1], g[2], g[3]);
            wq[1] = make_float4(g[4], g[5], g[6], g[7]);
            wq[2] = make_float4(g[8], g[9], g[10], g[11]);
            wq[3] = make_float4(g[12], g[13], g[14], g[15]);
        }
    }
}

extern "C" void kernel_launch(void* const* d_in, const int* in_sizes, int n_in,
                              void* d_out, int out_size, void* d_ws, size_t ws_size,
                              hipStream_t stream) {
    const float* flow   = (const float*)d_in[0];
    const float* emb    = (const float*)d_in[1];
    const float* cheb_w = (const float*)d_in[2];
    const float* cheb_b = (const float*)d_in[3];
    const float* cou_w  = (const float*)d_in[4];
    const float* gl_out = (const float*)d_in[5];
    const float* gl_fk  = (const float*)d_in[6];
    const float* gl_tzw = (const float*)d_in[7];
    const float* gl_tzb = (const float*)d_in[8];
    const float* Wih    = (const float*)d_in[9];
    const float* lb     = (const float*)d_in[10];
    const float* w2     = (const float*)d_in[11];
    const float* c_w    = (const float*)d_in[12];
    const float* c_b    = (const float*)d_in[13];
    const float* c1_w   = (const float*)d_in[14];
    const float* c1_b   = (const float*)d_in[15];
    float* out = (float*)d_out;
    float* ws  = (float*)d_ws;

    float* Ut  = ws;            // 10*324 = 3240 floats (zero-padded)
    float* WiT = ws + 3264;
    float* WgT = WiT + 512;
    float* WoT = WgT + 512;

    k_setup<<<1, 320, 0, stream>>>(emb, Wih, Ut, WiT, WgT, WoT);
    k_gl<<<BATCH, 320, 0, stream>>>(flow, Ut, cheb_w, cheb_b, cou_w,
                                    gl_out, gl_fk, gl_tzw, gl_tzb,
                                    c_w, c_b, c1_w, c1_b, out);
    k_nl<<<(NITEM * 4) / 256, 256, 0, stream>>>(WiT, WgT, WoT, lb, w2, out);
}

// Round 6
// 6494.027 us; speedup vs baseline: 1.2248x; 1.2248x over previous
//
#include <hip/hip_runtime.h>

#define N 307
#define CIN 5
#define HID 16
#define KORD 6
#define LH 32
#define BATCH 512
#define NP 324          // padded node stride, float4-aligned; zero-padded tail
#define NITEM (BATCH * N)   // 157184; x4 lanes = 628736 = 2456 * 256 exactly

__device__ __forceinline__ float sigmoidf(float x) {
    return __fdividef(1.f, 1.f + __expf(-x));
}
__device__ __forceinline__ float ftanh(float x) {
    float e = __expf(2.f * x);
    return 1.f - __fdividef(2.f, e + 1.f);
}

// ---------------- setup: U^T [10][NP] (L = I - U U^T), zero-padded; LSTM transposes ----------------
__global__ __launch_bounds__(320) void k_setup(const float* __restrict__ E,
                                               const float* __restrict__ Wih,
                                               float* __restrict__ Ut,
                                               float* __restrict__ WiT,
                                               float* __restrict__ WgT,
                                               float* __restrict__ WoT) {
    __shared__ float EnS[N * 10];
    __shared__ float sS[10];
    __shared__ float dS[N];
    const int t = threadIdx.x;
    if (t < N) {
        float v[10]; float nrm = 0.f;
        #pragma unroll
        for (int p = 0; p < 10; p++) { v[p] = E[t * 10 + p]; nrm = fmaf(v[p], v[p], nrm); }
        float r = rsqrtf(nrm);
        #pragma unroll
        for (int p = 0; p < 10; p++) EnS[t * 10 + p] = v[p] * r;
    }
    __syncthreads();
    if (t < 10) {
        float s = 0.f;
        for (int nn = 0; nn < N; nn++) s += EnS[nn * 10 + t];
        sS[t] = s;
    }
    __syncthreads();
    if (t < N) {
        float dot = 0.f;
        #pragma unroll
        for (int p = 0; p < 10; p++) dot = fmaf(EnS[t * 10 + p], sS[p], dot);
        dS[t] = rsqrtf(dot);
    }
    __syncthreads();
    for (int i = t; i < 10 * NP; i += 320) {
        int p = i / NP, nn = i - p * NP;
        Ut[i] = (nn < N) ? dS[nn] * EnS[nn * 10 + p] : 0.f;
    }
    for (int i = t; i < LH * HID; i += 320) {
        int j = i >> 4, h = i & 15;
        WiT[i] = Wih[h * 4 * LH + j];
        WgT[i] = Wih[h * 4 * LH + 2 * LH + j];
        WoT[i] = Wih[h * 4 * LH + 3 * LH + j];
    }
}

// ---------------- S[p*5+c] = sum_n U[n,p]*X[n,c]; 6 segments of 52 ----------------
__device__ __forceinline__ void reduce5(const float* __restrict__ Ub,
                                        const float* __restrict__ Xb,
                                        float* __restrict__ Sp,
                                        float* __restrict__ Sb, int t) {
    const int o = t % 50, sg = t / 50;
    if (sg < 6) {
        const int p = o / 5, c = o - (o / 5) * 5;
        int n0 = sg * 52, n1 = n0 + 52; if (n1 > N) n1 = N;
        const float* up = Ub + p * NP;
        const float* xp = Xb + c * NP;
        float acc = 0.f;
        #pragma unroll 4
        for (int nn = n0; nn < n1; nn++) acc = fmaf(up[nn], xp[nn], acc);
        Sp[t] = acc;
    }
    __syncthreads();
    if (t < 50) {
        float s = 0.f;
        #pragma unroll
        for (int sgi = 0; sgi < 6; sgi++) s += Sp[t + 50 * sgi];
        Sb[t] = s;
    }
    __syncthreads();
}

// ---------------- S[p*16+h] = sum_n U[n,p]*V[n,h]; float4, 2 segments of 160 ----------------
__device__ __forceinline__ void reduce16(const float* __restrict__ Ub,
                                         const float* __restrict__ Vb,
                                         float* __restrict__ Sp,
                                         float* __restrict__ Sb, int t) {
    const int o = t % 160, sg = t / 160;     // sg in {0,1}
    const int p = o >> 4, c = o & 15;
    const float4* up = (const float4*)(Ub + p * NP + sg * 160);
    const float4* xp = (const float4*)(Vb + c * NP + sg * 160);
    float a0 = 0.f, a1 = 0.f;
    #pragma unroll 8
    for (int q = 0; q < 40; q += 2) {
        float4 u0 = up[q], x0 = xp[q];
        a0 = fmaf(u0.x, x0.x, a0); a0 = fmaf(u0.y, x0.y, a0);
        a0 = fmaf(u0.z, x0.z, a0); a0 = fmaf(u0.w, x0.w, a0);
        float4 u1 = up[q + 1], x1 = xp[q + 1];
        a1 = fmaf(u1.x, x1.x, a1); a1 = fmaf(u1.y, x1.y, a1);
        a1 = fmaf(u1.z, x1.z, a1); a1 = fmaf(u1.w, x1.w, a1);
    }
    Sp[t] = a0 + a1;
    __syncthreads();
    if (t < 160) Sb[t] = Sp[t] + Sp[t + 160];
    __syncthreads();
}

// ---------------- GL core: z = GL(v), full-width, Sb via broadcast reads ----------------
__device__ __forceinline__ void glcore(const float* __restrict__ v,
                                       const float* __restrict__ U,
                                       const float* __restrict__ Sb,
                                       const float* __restrict__ wo,
                                       const float* __restrict__ wf,
                                       const float* __restrict__ wt,
                                       const float* __restrict__ bt,
                                       float* __restrict__ z) {
    float o1[HID];
    #pragma unroll
    for (int h = 0; h < HID; h++) o1[h] = v[h];
    #pragma unroll
    for (int p = 0; p < 10; p++) {
        float u = U[p];
        const float4* srow = (const float4*)(Sb + p * HID);
        float4 s0 = srow[0], s1 = srow[1], s2 = srow[2], s3 = srow[3];
        o1[0]  = fmaf(-u, s0.x, o1[0]);  o1[1]  = fmaf(-u, s0.y, o1[1]);
        o1[2]  = fmaf(-u, s0.z, o1[2]);  o1[3]  = fmaf(-u, s0.w, o1[3]);
        o1[4]  = fmaf(-u, s1.x, o1[4]);  o1[5]  = fmaf(-u, s1.y, o1[5]);
        o1[6]  = fmaf(-u, s1.z, o1[6]);  o1[7]  = fmaf(-u, s1.w, o1[7]);
        o1[8]  = fmaf(-u, s2.x, o1[8]);  o1[9]  = fmaf(-u, s2.y, o1[9]);
        o1[10] = fmaf(-u, s2.z, o1[10]); o1[11] = fmaf(-u, s2.w, o1[11]);
        o1[12] = fmaf(-u, s3.x, o1[12]); o1[13] = fmaf(-u, s3.y, o1[13]);
        o1[14] = fmaf(-u, s3.z, o1[14]); o1[15] = fmaf(-u, s3.w, o1[15]);
    }
    float y[HID] = {};
    #pragma unroll
    for (int h2 = 0; h2 < HID; h2++) {
        float xv = v[h2];
        #pragma unroll
        for (int h = 0; h < HID; h++) y[h] = fmaf(xv, wo[h2 * HID + h], y[h]);
    }
    #pragma unroll
    for (int h = 0; h < HID; h++) y[h] = ftanh(y[h]);
    float y2[HID] = {};
    #pragma unroll
    for (int h2 = 0; h2 < HID; h2++) {
        float xv = y[h2];
        #pragma unroll
        for (int h = 0; h < HID; h++) y2[h] = fmaf(xv, wf[h2 * HID + h], y2[h]);
    }
    #pragma unroll
    for (int h = 0; h < HID; h++) z[h] = bt[h];
    #pragma unroll
    for (int h2 = 0; h2 < HID; h2++) {
        float vv = o1[h2] - ftanh(y2[h2]);
        #pragma unroll
        for (int h = 0; h < HID; h++) z[h] = fmaf(vv, wt[h2 * HID + h], z[h]);
    }
}

// ---------------- kernel 1: init + cheb + 10x GL + cstep; writes s00/s11/step1 into out ----------------
__global__ __launch_bounds__(320, 5) void k_gl(
    const float* __restrict__ flow, const float* __restrict__ Ut,
    const float* __restrict__ cheb_w, const float* __restrict__ cheb_b,
    const float* __restrict__ cou_w,
    const float* __restrict__ gl_wo, const float* __restrict__ gl_wf,
    const float* __restrict__ gl_wt, const float* __restrict__ gl_bt,
    const float* __restrict__ c_w, const float* __restrict__ c_b,
    const float* __restrict__ c1_w, const float* __restrict__ c1_b,
    float* __restrict__ out) {
    __shared__ __align__(16) float Ub[10 * NP];
    __shared__ __align__(16) float Vb[HID * NP];
    __shared__ __align__(16) float Sp[320];
    __shared__ __align__(16) float Sb[10 * HID];
    const int t = threadIdx.x, b = blockIdx.x;
    const bool act = t < N;

    for (int i = t; i < 10 * NP; i += 320) Ub[i] = Ut[i];
    for (int i = t; i < HID * NP; i += 320) Vb[i] = 0.f;   // pad stays 0 forever
    __syncthreads();
    for (int i = t; i < N * CIN; i += 320) {
        int nn = i / CIN, c = i - nn * CIN;
        Vb[c * NP + nn] = flow[(size_t)b * N * CIN + i];
    }
    __syncthreads();

    float U[10], prev2[HID], cur[HID], tk0[CIN], tk1[CIN];
    if (act) {
        #pragma unroll
        for (int p = 0; p < 10; p++) U[p] = Ub[p * NP + t];
        float xv[CIN];
        #pragma unroll
        for (int c = 0; c < CIN; c++) { xv[c] = Vb[c * NP + t]; tk0[c] = xv[c]; }
        #pragma unroll
        for (int h = 0; h < HID; h++) {
            float s = 0.f, s2 = cheb_b[h];
            #pragma unroll
            for (int c = 0; c < CIN; c++) {
                s = fmaf(xv[c], cou_w[c * HID + h], s);
                s2 = fmaf(xv[c], cheb_w[c * HID + h], s2);   // k=0: T0@x = x
            }
            prev2[h] = s;
            cur[h] = s2;
        }
    }
    reduce5(Ub, Vb, Sp, Sb, t);
    if (act) {
        #pragma unroll
        for (int c = 0; c < CIN; c++) {
            float s = tk0[c];
            #pragma unroll
            for (int p = 0; p < 10; p++) s = fmaf(-U[p], Sb[p * CIN + c], s);
            tk1[c] = s;
        }
        #pragma unroll
        for (int c = 0; c < CIN; c++) {
            float v = tk1[c];
            #pragma unroll
            for (int h = 0; h < HID; h++)
                cur[h] = fmaf(v, cheb_w[CIN * HID + c * HID + h], cur[h]);
        }
    }
    for (int k = 2; k < KORD; k++) {
        if (act) {
            #pragma unroll
            for (int c = 0; c < CIN; c++) Vb[c * NP + t] = tk1[c];
        }
        __syncthreads();
        reduce5(Ub, Vb, Sp, Sb, t);
        if (act) {
            #pragma unroll
            for (int c = 0; c < CIN; c++) {
                float lt = tk1[c];
                #pragma unroll
                for (int p = 0; p < 10; p++) lt = fmaf(-U[p], Sb[p * CIN + c], lt);
                float tn = 2.f * lt - tk0[c];
                tk0[c] = tk1[c];
                tk1[c] = tn;
            }
            #pragma unroll
            for (int c = 0; c < CIN; c++) {
                float v = tk1[c];
                #pragma unroll
                for (int h = 0; h < HID; h++)
                    cur[h] = fmaf(v, cheb_w[(k * CIN + c) * HID + h], cur[h]);
            }
        }
    }

    // ---- GL chain: 10 iters x 2 evals; 3 barriers per eval ----
    for (int it = 0; it < 10; it++) {
        if (act) {
            #pragma unroll
            for (int h = 0; h < HID; h++) Vb[h * NP + t] = cur[h];
        }
        __syncthreads();
        reduce16(Ub, Vb, Sp, Sb, t);
        float tt[HID], wv[HID];
        if (act) {
            glcore(cur, U, Sb, gl_wo, gl_wf, gl_wt, gl_bt, tt);
            #pragma unroll
            for (int h = 0; h < HID; h++) wv[h] = fmaf(2.f, tt[h], prev2[h]);
            #pragma unroll
            for (int h = 0; h < HID; h++) Vb[h * NP + t] = wv[h];
        }
        __syncthreads();
        reduce16(Ub, Vb, Sp, Sb, t);
        if (act) {
            float uu[HID];
            glcore(wv, U, Sb, gl_wo, gl_wf, gl_wt, gl_bt, uu);
            #pragma unroll
            for (int h = 0; h < HID; h++) {
                float nc = cur[h] + 0.5f * (tt[h] + uu[h]);
                prev2[h] = cur[h];
                cur[h] = nc;
            }
        }
    }

    // ---- cstep; stash s00/s11/step1 in out slots 0/1/2 (k_nl overwrites) ----
    if (act) {
        float s00[HID], s11[HID];
        #pragma unroll
        for (int h = 0; h < HID; h++) { s00[h] = c_b[h]; s11[h] = c1_b[h]; }
        #pragma unroll
        for (int h2 = 0; h2 < HID; h2++) {
            float a = prev2[h2], c2v = cur[h2];
            #pragma unroll
            for (int h = 0; h < HID; h++) {
                s00[h] = fmaf(a, c_w[h2 * HID + h], s00[h]);
                s11[h] = fmaf(c2v, c1_w[h2 * HID + h], s11[h]);
            }
        }
        float* ob = out + (size_t)(b * N + t) * 160;
        float4* wq = (float4*)ob;
        wq[0] = make_float4(s00[0], s00[1], s00[2], s00[3]);
        wq[1] = make_float4(s00[4], s00[5], s00[6], s00[7]);
        wq[2] = make_float4(s00[8], s00[9], s00[10], s00[11]);
        wq[3] = make_float4(s00[12], s00[13], s00[14], s00[15]);
        wq[4] = make_float4(s11[0], s11[1], s11[2], s11[3]);
        wq[5] = make_float4(s11[4], s11[5], s11[6], s11[7]);
        wq[6] = make_float4(s11[8], s11[9], s11[10], s11[11]);
        wq[7] = make_float4(s11[12], s11[13], s11[14], s11[15]);
        wq[8] = make_float4(cur[0], cur[1], cur[2], cur[3]);
        wq[9] = make_float4(cur[4], cur[5], cur[6], cur[7]);
        wq[10] = make_float4(cur[8], cur[9], cur[10], cur[11]);
        wq[11] = make_float4(cur[12], cur[13], cur[14], cur[15]);
    }
}

// ---------------- NL quarter-eval: 8 of 32 LSTM rows per lane + quad combine ----------------
// biases reloaded from bih each call (L1-resident) to keep persistent VGPRs low
__device__ __forceinline__ void nl_eval_q(const float* __restrict__ x,
                                          const float* __restrict__ wi,
                                          const float* __restrict__ wg,
                                          const float* __restrict__ wo,
                                          const float* __restrict__ w2s,
                                          const float* __restrict__ bih,
                                          int j0,
                                          float* __restrict__ outv) {
    float part[HID];
    #pragma unroll
    for (int h = 0; h < HID; h++) part[h] = 0.f;
    #pragma unroll
    for (int jj = 0; jj < 8; jj++) {
        float gi = bih[j0 + jj];
        float gg = bih[2 * LH + j0 + jj];
        float go = bih[3 * LH + j0 + jj];
        const float4* wiq = (const float4*)(wi + jj * HID);
        const float4* wgq = (const float4*)(wg + jj * HID);
        const float4* woq = (const float4*)(wo + jj * HID);
        #pragma unroll
        for (int q = 0; q < 4; q++) {
            float4 a = wiq[q], bb = wgq[q], cc = woq[q];
            gi = fmaf(x[4 * q + 0], a.x, gi); gi = fmaf(x[4 * q + 1], a.y, gi);
            gi = fmaf(x[4 * q + 2], a.z, gi); gi = fmaf(x[4 * q + 3], a.w, gi);
            gg = fmaf(x[4 * q + 0], bb.x, gg); gg = fmaf(x[4 * q + 1], bb.y, gg);
            gg = fmaf(x[4 * q + 2], bb.z, gg); gg = fmaf(x[4 * q + 3], bb.w, gg);
            go = fmaf(x[4 * q + 0], cc.x, go); go = fmaf(x[4 * q + 1], cc.y, go);
            go = fmaf(x[4 * q + 2], cc.z, go); go = fmaf(x[4 * q + 3], cc.w, go);
        }
        float c = sigmoidf(gi) * ftanh(gg);
        float hh = sigmoidf(go) * ftanh(c);
        float th = ftanh(hh);
        const float4* w2q = (const float4*)(w2s + jj * HID);
        #pragma unroll
        for (int q = 0; q < 4; q++) {
            float4 a = w2q[q];
            part[4 * q + 0] = fmaf(th, a.x, part[4 * q + 0]);
            part[4 * q + 1] = fmaf(th, a.y, part[4 * q + 1]);
            part[4 * q + 2] = fmaf(th, a.z, part[4 * q + 2]);
            part[4 * q + 3] = fmaf(th, a.w, part[4 * q + 3]);
        }
    }
    // quad combine: lanes {4k..4k+3} sum their partials; all get the full result
    #pragma unroll
    for (int h = 0; h < HID; h++) {
        float v = part[h];
        v += __shfl_xor(v, 1);
        v += __shfl_xor(v, 2);
        outv[h] = v;
    }
}

// ---------------- kernel 2: NL chain, 4 lanes/item; no LDS, no barriers ----------------
__global__ __launch_bounds__(256, 4) void k_nl(
    const float* __restrict__ WiT, const float* __restrict__ WgT,
    const float* __restrict__ WoT, const float* __restrict__ bih,
    const float* __restrict__ w2, float* __restrict__ out) {
    const int gt = blockIdx.x * 256 + threadIdx.x;
    const int item = gt >> 2, sub = gt & 3;
    if (item >= NITEM) return;
    float* ob = out + (size_t)item * 160;

    const int j0 = sub * 8;
    const float* wi = WiT + j0 * HID;
    const float* wg = WgT + j0 * HID;
    const float* wo = WoT + j0 * HID;
    const float* w2s = w2 + j0 * HID;

    float s00[HID], s11[HID], curf[HID];
    {
        const float4* rq = (const float4*)ob;
        float4 a0 = rq[0], a1 = rq[1], a2 = rq[2], a3 = rq[3];
        float4 b0 = rq[4], b1 = rq[5], b2 = rq[6], b3 = rq[7];
        float4 c0 = rq[8], c1 = rq[9], c2 = rq[10], c3 = rq[11];
        s00[0] = a0.x; s00[1] = a0.y; s00[2] = a0.z; s00[3] = a0.w;
        s00[4] = a1.x; s00[5] = a1.y; s00[6] = a1.z; s00[7] = a1.w;
        s00[8] = a2.x; s00[9] = a2.y; s00[10] = a2.z; s00[11] = a2.w;
        s00[12] = a3.x; s00[13] = a3.y; s00[14] = a3.z; s00[15] = a3.w;
        s11[0] = b0.x; s11[1] = b0.y; s11[2] = b0.z; s11[3] = b0.w;
        s11[4] = b1.x; s11[5] = b1.y; s11[6] = b1.z; s11[7] = b1.w;
        s11[8] = b2.x; s11[9] = b2.y; s11[10] = b2.z; s11[11] = b2.w;
        s11[12] = b3.x; s11[13] = b3.y; s11[14] = b3.z; s11[15] = b3.w;
        curf[0] = c0.x; curf[1] = c0.y; curf[2] = c0.z; curf[3] = c0.w;
        curf[4] = c1.x; curf[5] = c1.y; curf[6] = c1.z; curf[7] = c1.w;
        curf[8] = c2.x; curf[9] = c2.y; curf[10] = c2.z; curf[11] = c2.w;
        curf[12] = c3.x; curf[13] = c3.y; curf[14] = c3.z; curf[15] = c3.w;
    }

    float tt[HID], uu[HID], g[HID], p2[HID];
    nl_eval_q(s11, wi, wg, wo, w2s, bih, j0, tt);
    #pragma unroll
    for (int h = 0; h < HID; h++) s00[h] = fmaf(2.f, tt[h], s00[h]);
    nl_eval_q(s00, wi, wg, wo, w2s, bih, j0, uu);
    #pragma unroll
    for (int h = 0; h < HID; h++) {
        g[h] = curf[h] + 0.5f * (tt[h] + uu[h]);
        p2[h] = s11[h];
    }
    if (sub == 0) {
        float4* wq = (float4*)ob;
        wq[0] = make_float4(g[0], g[1], g[2], g[3]);
        wq[1] = make_float4(g[4], g[5], g[6], g[7]);
        wq[2] = make_float4(g[8], g[9], g[10], g[11]);
        wq[3] = make_float4(g[12], g[13], g[14], g[15]);
    }
    for (int i = 1; i < 10; i++) {
        nl_eval_q(g, wi, wg, wo, w2s, bih, j0, tt);
        #pragma unroll
        for (int h = 0; h < HID; h++) p2[h] = fmaf(2.f, tt[h], p2[h]);   // p2 := tmp
        nl_eval_q(p2, wi, wg, wo, w2s, bih, j0, uu);
        #pragma unroll
        for (int h = 0; h < HID; h++) {
            float ng = g[h] + 0.5f * (tt[h] + uu[h]);
            p2[h] = g[h];
            g[h] = ng;
        }
        if (sub == 0) {
            float4* wq = (float4*)(ob + i * HID);
            wq[0] = make_float4(g[0], g[1], g[2], g[3]);
            wq[1] = make_float4(g[4], g[5], g[6], g[7]);
            wq[2] = make_float4(g[8], g[9], g[10], g[11]);
            wq[3] = make_float4(g[12], g[13], g[14], g[15]);
        }
    }
}

extern "C" void kernel_launch(void* const* d_in, const int* in_sizes, int n_in,
                              void* d_out, int out_size, void* d_ws, size_t ws_size,
                              hipStream_t stream) {
    const float* flow   = (const float*)d_in[0];
    const float* emb    = (const float*)d_in[1];
    const float* cheb_w = (const float*)d_in[2];
    const float* cheb_b = (const float*)d_in[3];
    const float* cou_w  = (const float*)d_in[4];
    const float* gl_out = (const float*)d_in[5];
    const float* gl_fk  = (const float*)d_in[6];
    const float* gl_tzw = (const float*)d_in[7];
    const float* gl_tzb = (const float*)d_in[8];
    const float* Wih    = (const float*)d_in[9];
    const float* lb     = (const float*)d_in[10];
    const float* w2     = (const float*)d_in[11];
    const float* c_w    = (const float*)d_in[12];
    const float* c_b    = (const float*)d_in[13];
    const float* c1_w   = (const float*)d_in[14];
    const float* c1_b   = (const float*)d_in[15];
    float* out = (float*)d_out;
    float* ws  = (float*)d_ws;

    float* Ut  = ws;            // 10*324 = 3240 floats (zero-padded)
    float* WiT = ws + 3264;
    float* WgT = WiT + 512;
    float* WoT = WgT + 512;

    k_setup<<<1, 320, 0, stream>>>(emb, Wih, Ut, WiT, WgT, WoT);
    k_gl<<<BATCH, 320, 0, stream>>>(flow, Ut, cheb_w, cheb_b, cou_w,
                                    gl_out, gl_fk, gl_tzw, gl_tzb,
                                    c_w, c_b, c1_w, c1_b, out);
    k_nl<<<(NITEM * 4) / 256, 256, 0, stream>>>(WiT, WgT, WoT, lb, w2, out);
}

// Round 8
// 1254.195 us; speedup vs baseline: 6.3418x; 5.1778x over previous
//
#include <hip/hip_runtime.h>

#define N 307
#define CIN 5
#define HID 16
#define KORD 6
#define LH 32
#define BATCH 512
#define NP 324          // padded node stride, float4-aligned; zero-padded tail
#define NITEM (BATCH * N)   // 157184 = 1228 * 128 exactly
#define NLB 1228
#define XS 17           // LDS exchange stride (odd -> 2-way max bank aliasing, free)

__device__ __forceinline__ float sigmoidf(float x) {
    return __fdividef(1.f, 1.f + __expf(-x));
}
__device__ __forceinline__ float ftanh(float x) {
    float e = __expf(2.f * x);
    return 1.f - __fdividef(2.f, e + 1.f);
}

// ---------------- setup: U^T [10][NP] (L = I - U U^T), zero-padded; LSTM transposes ----------------
__global__ __launch_bounds__(320) void k_setup(const float* __restrict__ E,
                                               const float* __restrict__ Wih,
                                               float* __restrict__ Ut,
                                               float* __restrict__ WiT,
                                               float* __restrict__ WgT,
                                               float* __restrict__ WoT) {
    __shared__ float EnS[N * 10];
    __shared__ float sS[10];
    __shared__ float dS[N];
    const int t = threadIdx.x;
    if (t < N) {
        float v[10]; float nrm = 0.f;
        #pragma unroll
        for (int p = 0; p < 10; p++) { v[p] = E[t * 10 + p]; nrm = fmaf(v[p], v[p], nrm); }
        float r = rsqrtf(nrm);
        #pragma unroll
        for (int p = 0; p < 10; p++) EnS[t * 10 + p] = v[p] * r;
    }
    __syncthreads();
    if (t < 10) {
        float s = 0.f;
        for (int nn = 0; nn < N; nn++) s += EnS[nn * 10 + t];
        sS[t] = s;
    }
    __syncthreads();
    if (t < N) {
        float dot = 0.f;
        #pragma unroll
        for (int p = 0; p < 10; p++) dot = fmaf(EnS[t * 10 + p], sS[p], dot);
        dS[t] = rsqrtf(dot);
    }
    __syncthreads();
    for (int i = t; i < 10 * NP; i += 320) {
        int p = i / NP, nn = i - p * NP;
        Ut[i] = (nn < N) ? dS[nn] * EnS[nn * 10 + p] : 0.f;
    }
    for (int i = t; i < LH * HID; i += 320) {
        int j = i >> 4, h = i & 15;
        WiT[i] = Wih[h * 4 * LH + j];
        WgT[i] = Wih[h * 4 * LH + 2 * LH + j];
        WoT[i] = Wih[h * 4 * LH + 3 * LH + j];
    }
}

// ---------------- S[p*5+c] = sum_n U[n,p]*X[n,c]; 6 segments of 52 ----------------
__device__ __forceinline__ void reduce5(const float* __restrict__ Ub,
                                        const float* __restrict__ Xb,
                                        float* __restrict__ Sp,
                                        float* __restrict__ Sb, int t) {
    const int o = t % 50, sg = t / 50;
    if (sg < 6) {
        const int p = o / 5, c = o - (o / 5) * 5;
        int n0 = sg * 52, n1 = n0 + 52; if (n1 > N) n1 = N;
        const float* up = Ub + p * NP;
        const float* xp = Xb + c * NP;
        float acc = 0.f;
        #pragma unroll 4
        for (int nn = n0; nn < n1; nn++) acc = fmaf(up[nn], xp[nn], acc);
        Sp[t] = acc;
    }
    __syncthreads();
    if (t < 50) {
        float s = 0.f;
        #pragma unroll
        for (int sgi = 0; sgi < 6; sgi++) s += Sp[t + 50 * sgi];
        Sb[t] = s;
    }
    __syncthreads();
}

// ---------------- S[p*16+h] = sum_n U[n,p]*V[n,h]; float4, 2 segments of 160 ----------------
__device__ __forceinline__ void reduce16(const float* __restrict__ Ub,
                                         const float* __restrict__ Vb,
                                         float* __restrict__ Sp,
                                         float* __restrict__ Sb, int t) {
    const int o = t % 160, sg = t / 160;     // sg in {0,1}
    const int p = o >> 4, c = o & 15;
    const float4* up = (const float4*)(Ub + p * NP + sg * 160);
    const float4* xp = (const float4*)(Vb + c * NP + sg * 160);
    float a0 = 0.f, a1 = 0.f;
    #pragma unroll 8
    for (int q = 0; q < 40; q += 2) {
        float4 u0 = up[q], x0 = xp[q];
        a0 = fmaf(u0.x, x0.x, a0); a0 = fmaf(u0.y, x0.y, a0);
        a0 = fmaf(u0.z, x0.z, a0); a0 = fmaf(u0.w, x0.w, a0);
        float4 u1 = up[q + 1], x1 = xp[q + 1];
        a1 = fmaf(u1.x, x1.x, a1); a1 = fmaf(u1.y, x1.y, a1);
        a1 = fmaf(u1.z, x1.z, a1); a1 = fmaf(u1.w, x1.w, a1);
    }
    Sp[t] = a0 + a1;
    __syncthreads();
    if (t < 160) Sb[t] = Sp[t] + Sp[t + 160];
    __syncthreads();
}

// ---------------- GL core: z = GL(v), full-width, Sb via broadcast reads ----------------
__device__ __forceinline__ void glcore(const float* __restrict__ v,
                                       const float* __restrict__ U,
                                       const float* __restrict__ Sb,
                                       const float* __restrict__ wo,
                                       const float* __restrict__ wf,
                                       const float* __restrict__ wt,
                                       const float* __restrict__ bt,
                                       float* __restrict__ z) {
    float o1[HID];
    #pragma unroll
    for (int h = 0; h < HID; h++) o1[h] = v[h];
    #pragma unroll
    for (int p = 0; p < 10; p++) {
        float u = U[p];
        const float4* srow = (const float4*)(Sb + p * HID);
        float4 s0 = srow[0], s1 = srow[1], s2 = srow[2], s3 = srow[3];
        o1[0]  = fmaf(-u, s0.x, o1[0]);  o1[1]  = fmaf(-u, s0.y, o1[1]);
        o1[2]  = fmaf(-u, s0.z, o1[2]);  o1[3]  = fmaf(-u, s0.w, o1[3]);
        o1[4]  = fmaf(-u, s1.x, o1[4]);  o1[5]  = fmaf(-u, s1.y, o1[5]);
        o1[6]  = fmaf(-u, s1.z, o1[6]);  o1[7]  = fmaf(-u, s1.w, o1[7]);
        o1[8]  = fmaf(-u, s2.x, o1[8]);  o1[9]  = fmaf(-u, s2.y, o1[9]);
        o1[10] = fmaf(-u, s2.z, o1[10]); o1[11] = fmaf(-u, s2.w, o1[11]);
        o1[12] = fmaf(-u, s3.x, o1[12]); o1[13] = fmaf(-u, s3.y, o1[13]);
        o1[14] = fmaf(-u, s3.z, o1[14]); o1[15] = fmaf(-u, s3.w, o1[15]);
    }
    float y[HID] = {};
    #pragma unroll
    for (int h2 = 0; h2 < HID; h2++) {
        float xv = v[h2];
        #pragma unroll
        for (int h = 0; h < HID; h++) y[h] = fmaf(xv, wo[h2 * HID + h], y[h]);
    }
    #pragma unroll
    for (int h = 0; h < HID; h++) y[h] = ftanh(y[h]);
    float y2[HID] = {};
    #pragma unroll
    for (int h2 = 0; h2 < HID; h2++) {
        float xv = y[h2];
        #pragma unroll
        for (int h = 0; h < HID; h++) y2[h] = fmaf(xv, wf[h2 * HID + h], y2[h]);
    }
    #pragma unroll
    for (int h = 0; h < HID; h++) z[h] = bt[h];
    #pragma unroll
    for (int h2 = 0; h2 < HID; h2++) {
        float vv = o1[h2] - ftanh(y2[h2]);
        #pragma unroll
        for (int h = 0; h < HID; h++) z[h] = fmaf(vv, wt[h2 * HID + h], z[h]);
    }
}

// ---------------- kernel 1: init + cheb + 10x GL + cstep; writes s00/s11/step1 into out ----------------
__global__ __launch_bounds__(320, 3) void k_gl(
    const float* __restrict__ flow, const float* __restrict__ Ut,
    const float* __restrict__ cheb_w, const float* __restrict__ cheb_b,
    const float* __restrict__ cou_w,
    const float* __restrict__ gl_wo, const float* __restrict__ gl_wf,
    const float* __restrict__ gl_wt, const float* __restrict__ gl_bt,
    const float* __restrict__ c_w, const float* __restrict__ c_b,
    const float* __restrict__ c1_w, const float* __restrict__ c1_b,
    float* __restrict__ out) {
    __shared__ __align__(16) float Ub[10 * NP];
    __shared__ __align__(16) float Vb[HID * NP];
    __shared__ __align__(16) float Sp[320];
    __shared__ __align__(16) float Sb[10 * HID];
    const int t = threadIdx.x, b = blockIdx.x;
    const bool act = t < N;

    for (int i = t; i < 10 * NP; i += 320) Ub[i] = Ut[i];
    for (int i = t; i < HID * NP; i += 320) Vb[i] = 0.f;   // pad stays 0 forever
    __syncthreads();
    for (int i = t; i < N * CIN; i += 320) {
        int nn = i / CIN, c = i - nn * CIN;
        Vb[c * NP + nn] = flow[(size_t)b * N * CIN + i];
    }
    __syncthreads();

    float U[10], prev2[HID], cur[HID], tk0[CIN], tk1[CIN];
    if (act) {
        #pragma unroll
        for (int p = 0; p < 10; p++) U[p] = Ub[p * NP + t];
        float xv[CIN];
        #pragma unroll
        for (int c = 0; c < CIN; c++) { xv[c] = Vb[c * NP + t]; tk0[c] = xv[c]; }
        #pragma unroll
        for (int h = 0; h < HID; h++) {
            float s = 0.f, s2 = cheb_b[h];
            #pragma unroll
            for (int c = 0; c < CIN; c++) {
                s = fmaf(xv[c], cou_w[c * HID + h], s);
                s2 = fmaf(xv[c], cheb_w[c * HID + h], s2);   // k=0: T0@x = x
            }
            prev2[h] = s;
            cur[h] = s2;
        }
    }
    reduce5(Ub, Vb, Sp, Sb, t);
    if (act) {
        #pragma unroll
        for (int c = 0; c < CIN; c++) {
            float s = tk0[c];
            #pragma unroll
            for (int p = 0; p < 10; p++) s = fmaf(-U[p], Sb[p * CIN + c], s);
            tk1[c] = s;
        }
        #pragma unroll
        for (int c = 0; c < CIN; c++) {
            float v = tk1[c];
            #pragma unroll
            for (int h = 0; h < HID; h++)
                cur[h] = fmaf(v, cheb_w[CIN * HID + c * HID + h], cur[h]);
        }
    }
    for (int k = 2; k < KORD; k++) {
        if (act) {
            #pragma unroll
            for (int c = 0; c < CIN; c++) Vb[c * NP + t] = tk1[c];
        }
        __syncthreads();
        reduce5(Ub, Vb, Sp, Sb, t);
        if (act) {
            #pragma unroll
            for (int c = 0; c < CIN; c++) {
                float lt = tk1[c];
                #pragma unroll
                for (int p = 0; p < 10; p++) lt = fmaf(-U[p], Sb[p * CIN + c], lt);
                float tn = 2.f * lt - tk0[c];
                tk0[c] = tk1[c];
                tk1[c] = tn;
            }
            #pragma unroll
            for (int c = 0; c < CIN; c++) {
                float v = tk1[c];
                #pragma unroll
                for (int h = 0; h < HID; h++)
                    cur[h] = fmaf(v, cheb_w[(k * CIN + c) * HID + h], cur[h]);
            }
        }
    }

    // ---- GL chain: 10 iters x 2 evals; 3 barriers per eval ----
    for (int it = 0; it < 10; it++) {
        if (act) {
            #pragma unroll
            for (int h = 0; h < HID; h++) Vb[h * NP + t] = cur[h];
        }
        __syncthreads();
        reduce16(Ub, Vb, Sp, Sb, t);
        float tt[HID], wv[HID];
        if (act) {
            glcore(cur, U, Sb, gl_wo, gl_wf, gl_wt, gl_bt, tt);
            #pragma unroll
            for (int h = 0; h < HID; h++) wv[h] = fmaf(2.f, tt[h], prev2[h]);
            #pragma unroll
            for (int h = 0; h < HID; h++) Vb[h * NP + t] = wv[h];
        }
        __syncthreads();
        reduce16(Ub, Vb, Sp, Sb, t);
        if (act) {
            float uu[HID];
            glcore(wv, U, Sb, gl_wo, gl_wf, gl_wt, gl_bt, uu);
            #pragma unroll
            for (int h = 0; h < HID; h++) {
                float nc = cur[h] + 0.5f * (tt[h] + uu[h]);
                prev2[h] = cur[h];
                cur[h] = nc;
            }
        }
    }

    // ---- cstep; stash s00/s11/step1 in out slots 0/1/2 (k_nl overwrites) ----
    if (act) {
        float s00[HID], s11[HID];
        #pragma unroll
        for (int h = 0; h < HID; h++) { s00[h] = c_b[h]; s11[h] = c1_b[h]; }
        #pragma unroll
        for (int h2 = 0; h2 < HID; h2++) {
            float a = prev2[h2], c2v = cur[h2];
            #pragma unroll
            for (int h = 0; h < HID; h++) {
                s00[h] = fmaf(a, c_w[h2 * HID + h], s00[h]);
                s11[h] = fmaf(c2v, c1_w[h2 * HID + h], s11[h]);
            }
        }
        float* ob = out + (size_t)(b * N + t) * 160;
        float4* wq = (float4*)ob;
        wq[0] = make_float4(s00[0], s00[1], s00[2], s00[3]);
        wq[1] = make_float4(s00[4], s00[5], s00[6], s00[7]);
        wq[2] = make_float4(s00[8], s00[9], s00[10], s00[11]);
        wq[3] = make_float4(s00[12], s00[13], s00[14], s00[15]);
        wq[4] = make_float4(s11[0], s11[1], s11[2], s11[3]);
        wq[5] = make_float4(s11[4], s11[5], s11[6], s11[7]);
        wq[6] = make_float4(s11[8], s11[9], s11[10], s11[11]);
        wq[7] = make_float4(s11[12], s11[13], s11[14], s11[15]);
        wq[8] = make_float4(cur[0], cur[1], cur[2], cur[3]);
        wq[9] = make_float4(cur[4], cur[5], cur[6], cur[7]);
        wq[10] = make_float4(cur[8], cur[9], cur[10], cur[11]);
        wq[11] = make_float4(cur[12], cur[13], cur[14], cur[15]);
    }
}

// ---------------- NL half-eval: 16 of 32 LSTM rows (wave-uniform j range -> s_load weights),
// then LDS exchange; both halves produce the bit-identical full sum ----------------
__device__ __forceinline__ void nl_eval_h(const float* __restrict__ x, int j0,
                                          const float* __restrict__ WiT,
                                          const float* __restrict__ WgT,
                                          const float* __restrict__ WoT,
                                          const float* __restrict__ w2,
                                          const float* __restrict__ bih,
                                          float* __restrict__ Xs,
                                          int slot, int half,
                                          float* __restrict__ outv) {
    float part[HID];
    #pragma unroll
    for (int h = 0; h < HID; h++) part[h] = 0.f;
    #pragma unroll 2
    for (int jj = 0; jj < 16; jj++) {
        const int j = j0 + jj;
        float gi = bih[j], gg = bih[2 * LH + j], go = bih[3 * LH + j];
        const float4* wi = (const float4*)(WiT + j * HID);
        const float4* wg = (const float4*)(WgT + j * HID);
        const float4* wo4 = (const float4*)(WoT + j * HID);
        #pragma unroll
        for (int q = 0; q < 4; q++) {
            float4 a = wi[q], bb = wg[q], cc = wo4[q];
            gi = fmaf(x[4 * q + 0], a.x, gi); gi = fmaf(x[4 * q + 1], a.y, gi);
            gi = fmaf(x[4 * q + 2], a.z, gi); gi = fmaf(x[4 * q + 3], a.w, gi);
            gg = fmaf(x[4 * q + 0], bb.x, gg); gg = fmaf(x[4 * q + 1], bb.y, gg);
            gg = fmaf(x[4 * q + 2], bb.z, gg); gg = fmaf(x[4 * q + 3], bb.w, gg);
            go = fmaf(x[4 * q + 0], cc.x, go); go = fmaf(x[4 * q + 1], cc.y, go);
            go = fmaf(x[4 * q + 2], cc.z, go); go = fmaf(x[4 * q + 3], cc.w, go);
        }
        float c = sigmoidf(gi) * ftanh(gg);
        float hh = sigmoidf(go) * ftanh(c);
        float th = ftanh(hh);
        const float4* w2r = (const float4*)(w2 + j * HID);
        #pragma unroll
        for (int q = 0; q < 4; q++) {
            float4 a = w2r[q];
            part[4 * q + 0] = fmaf(th, a.x, part[4 * q + 0]);
            part[4 * q + 1] = fmaf(th, a.y, part[4 * q + 1]);
            part[4 * q + 2] = fmaf(th, a.z, part[4 * q + 2]);
            part[4 * q + 3] = fmaf(th, a.w, part[4 * q + 3]);
        }
    }
    // exchange: write own partial, read both regions in canonical order
    float* my = Xs + half * (128 * XS) + slot * XS;
    #pragma unroll
    for (int h = 0; h < HID; h++) my[h] = part[h];
    __syncthreads();
    const float* r0 = Xs + slot * XS;
    const float* r1 = Xs + 128 * XS + slot * XS;
    #pragma unroll
    for (int h = 0; h < HID; h++) outv[h] = r0[h] + r1[h];
    __syncthreads();   // guard: all reads done before next eval overwrites
}

// ---------------- kernel 2: NL chain; 2 wave-groups per 128 items, row-split ----------------
__global__ __launch_bounds__(256, 3) void k_nl(
    const float* __restrict__ WiT, const float* __restrict__ WgT,
    const float* __restrict__ WoT, const float* __restrict__ bih,
    const float* __restrict__ w2, float* __restrict__ out) {
    __shared__ float Xs[2 * 128 * XS];   // 17408 B
    const int t = threadIdx.x;
    const int half = t >> 7;             // waves 0-1: rows 0-15; waves 2-3: rows 16-31
    const int slot = t & 127;
    const int item = blockIdx.x * 128 + slot;   // 1228*128 == NITEM exactly
    const int j0 = half * 16;
    float* ob = out + (size_t)item * 160;

    float s00[HID], s11[HID], curf[HID];
    {
        const float4* rq = (const float4*)ob;
        float4 a0 = rq[0], a1 = rq[1], a2 = rq[2], a3 = rq[3];
        float4 b0 = rq[4], b1 = rq[5], b2 = rq[6], b3 = rq[7];
        float4 c0 = rq[8], c1 = rq[9], c2 = rq[10], c3 = rq[11];
        s00[0] = a0.x; s00[1] = a0.y; s00[2] = a0.z; s00[3] = a0.w;
        s00[4] = a1.x; s00[5] = a1.y; s00[6] = a1.z; s00[7] = a1.w;
        s00[8] = a2.x; s00[9] = a2.y; s00[10] = a2.z; s00[11] = a2.w;
        s00[12] = a3.x; s00[13] = a3.y; s00[14] = a3.z; s00[15] = a3.w;
        s11[0] = b0.x; s11[1] = b0.y; s11[2] = b0.z; s11[3] = b0.w;
        s11[4] = b1.x; s11[5] = b1.y; s11[6] = b1.z; s11[7] = b1.w;
        s11[8] = b2.x; s11[9] = b2.y; s11[10] = b2.z; s11[11] = b2.w;
        s11[12] = b3.x; s11[13] = b3.y; s11[14] = b3.z; s11[15] = b3.w;
        curf[0] = c0.x; curf[1] = c0.y; curf[2] = c0.z; curf[3] = c0.w;
        curf[4] = c1.x; curf[5] = c1.y; curf[6] = c1.z; curf[7] = c1.w;
        curf[8] = c2.x; curf[9] = c2.y; curf[10] = c2.z; curf[11] = c2.w;
        curf[12] = c3.x; curf[13] = c3.y; curf[14] = c3.z; curf[15] = c3.w;
    }

    float tt[HID], uu[HID], g[HID], p2[HID];
    nl_eval_h(s11, j0, WiT, WgT, WoT, w2, bih, Xs, slot, half, tt);
    #pragma unroll
    for (int h = 0; h < HID; h++) s00[h] = fmaf(2.f, tt[h], s00[h]);
    nl_eval_h(s00, j0, WiT, WgT, WoT, w2, bih, Xs, slot, half, uu);
    #pragma unroll
    for (int h = 0; h < HID; h++) {
        g[h] = curf[h] + 0.5f * (tt[h] + uu[h]);
        p2[h] = s11[h];
    }
    if (half == 0) {
        float4* wq = (float4*)ob;
        wq[0] = make_float4(g[0], g[1], g[2], g[3]);
        wq[1] = make_float4(g[4], g[5], g[6], g[7]);
        wq[2] = make_float4(g[8], g[9], g[10], g[11]);
        wq[3] = make_float4(g[12], g[13], g[14], g[15]);
    }
    for (int i = 1; i < 10; i++) {
        nl_eval_h(g, j0, WiT, WgT, WoT, w2, bih, Xs, slot, half, tt);
        #pragma unroll
        for (int h = 0; h < HID; h++) p2[h] = fmaf(2.f, tt[h], p2[h]);   // p2 := tmp
        nl_eval_h(p2, j0, WiT, WgT, WoT, w2, bih, Xs, slot, half, uu);
        #pragma unroll
        for (int h = 0; h < HID; h++) {
            float ng = g[h] + 0.5f * (tt[h] + uu[h]);
            p2[h] = g[h];
            g[h] = ng;
        }
        if (half == 0) {
            float4* wq = (float4*)(ob + i * HID);
            wq[0] = make_float4(g[0], g[1], g[2], g[3]);
            wq[1] = make_float4(g[4], g[5], g[6], g[7]);
            wq[2] = make_float4(g[8], g[9], g[10], g[11]);
            wq[3] = make_float4(g[12], g[13], g[14], g[15]);
        }
    }
}

extern "C" void kernel_launch(void* const* d_in, const int* in_sizes, int n_in,
                              void* d_out, int out_size, void* d_ws, size_t ws_size,
                              hipStream_t stream) {
    const float* flow   = (const float*)d_in[0];
    const float* emb    = (const float*)d_in[1];
    const float* cheb_w = (const float*)d_in[2];
    const float* cheb_b = (const float*)d_in[3];
    const float* cou_w  = (const float*)d_in[4];
    const float* gl_out = (const float*)d_in[5];
    const float* gl_fk  = (const float*)d_in[6];
    const float* gl_tzw = (const float*)d_in[7];
    const float* gl_tzb = (const float*)d_in[8];
    const float* Wih    = (const float*)d_in[9];
    const float* lb     = (const float*)d_in[10];
    const float* w2     = (const float*)d_in[11];
    const float* c_w    = (const float*)d_in[12];
    const float* c_b    = (const float*)d_in[13];
    const float* c1_w   = (const float*)d_in[14];
    const float* c1_b   = (const float*)d_in[15];
    float* out = (float*)d_out;
    float* ws  = (float*)d_ws;

    float* Ut  = ws;            // 10*324 = 3240 floats (zero-padded)
    float* WiT = ws + 3264;
    float* WgT = WiT + 512;
    float* WoT = WgT + 512;

    k_setup<<<1, 320, 0, stream>>>(emb, Wih, Ut, WiT, WgT, WoT);
    k_gl<<<BATCH, 320, 0, stream>>>(flow, Ut, cheb_w, cheb_b, cou_w,
                                    gl_out, gl_fk, gl_tzw, gl_tzb,
                                    c_w, c_b, c1_w, c1_b, out);
    k_nl<<<NLB, 256, 0, stream>>>(WiT, WgT, WoT, lb, w2, out);
}

// Round 9
// 1067.109 us; speedup vs baseline: 7.4536x; 1.1753x over previous
//
#include <hip/hip_runtime.h>

#define N 307
#define CIN 5
#define HID 16
#define KORD 6
#define LH 32
#define BATCH 512
#define NP 324          // padded node stride, float4-aligned; zero-padded tail
#define NITEM (BATCH * N)   // 157184
#define NH (NITEM / 2)      // 78592 = 614 * 128 exactly

__device__ __forceinline__ float sigmoidf(float x) {
    return __fdividef(1.f, 1.f + __expf(-x));
}
__device__ __forceinline__ float ftanh(float x) {
    float e = __expf(2.f * x);
    return 1.f - __fdividef(2.f, e + 1.f);
}

// ---------------- setup: U^T [10][NP] (L = I - U U^T), zero-padded; LSTM transposes ----------------
__global__ __launch_bounds__(320) void k_setup(const float* __restrict__ E,
                                               const float* __restrict__ Wih,
                                               float* __restrict__ Ut,
                                               float* __restrict__ WiT,
                                               float* __restrict__ WgT,
                                               float* __restrict__ WoT) {
    __shared__ float EnS[N * 10];
    __shared__ float sS[10];
    __shared__ float dS[N];
    const int t = threadIdx.x;
    if (t < N) {
        float v[10]; float nrm = 0.f;
        #pragma unroll
        for (int p = 0; p < 10; p++) { v[p] = E[t * 10 + p]; nrm = fmaf(v[p], v[p], nrm); }
        float r = rsqrtf(nrm);
        #pragma unroll
        for (int p = 0; p < 10; p++) EnS[t * 10 + p] = v[p] * r;
    }
    __syncthreads();
    if (t < 10) {
        float s = 0.f;
        for (int nn = 0; nn < N; nn++) s += EnS[nn * 10 + t];
        sS[t] = s;
    }
    __syncthreads();
    if (t < N) {
        float dot = 0.f;
        #pragma unroll
        for (int p = 0; p < 10; p++) dot = fmaf(EnS[t * 10 + p], sS[p], dot);
        dS[t] = rsqrtf(dot);
    }
    __syncthreads();
    for (int i = t; i < 10 * NP; i += 320) {
        int p = i / NP, nn = i - p * NP;
        Ut[i] = (nn < N) ? dS[nn] * EnS[nn * 10 + p] : 0.f;
    }
    for (int i = t; i < LH * HID; i += 320) {
        int j = i >> 4, h = i & 15;
        WiT[i] = Wih[h * 4 * LH + j];
        WgT[i] = Wih[h * 4 * LH + 2 * LH + j];
        WoT[i] = Wih[h * 4 * LH + 3 * LH + j];
    }
}

// ---------------- S[p*5+c] = sum_n U[n,p]*X[n,c]; 6 segments of 52 ----------------
__device__ __forceinline__ void reduce5(const float* __restrict__ Ub,
                                        const float* __restrict__ Xb,
                                        float* __restrict__ Sp,
                                        float* __restrict__ Sb, int t) {
    const int o = t % 50, sg = t / 50;
    if (sg < 6) {
        const int p = o / 5, c = o - (o / 5) * 5;
        int n0 = sg * 52, n1 = n0 + 52; if (n1 > N) n1 = N;
        const float* up = Ub + p * NP;
        const float* xp = Xb + c * NP;
        float acc = 0.f;
        #pragma unroll 4
        for (int nn = n0; nn < n1; nn++) acc = fmaf(up[nn], xp[nn], acc);
        Sp[t] = acc;
    }
    __syncthreads();
    if (t < 50) {
        float s = 0.f;
        #pragma unroll
        for (int sgi = 0; sgi < 6; sgi++) s += Sp[t + 50 * sgi];
        Sb[t] = s;
    }
    __syncthreads();
}

// ---------------- S[p*16+h] = sum_n U[n,p]*V[n,h]; float4, 2 segments of 160 ----------------
__device__ __forceinline__ void reduce16(const float* __restrict__ Ub,
                                         const float* __restrict__ Vb,
                                         float* __restrict__ Sp,
                                         float* __restrict__ Sb, int t) {
    const int o = t % 160, sg = t / 160;     // sg in {0,1}
    const int p = o >> 4, c = o & 15;
    const float4* up = (const float4*)(Ub + p * NP + sg * 160);
    const float4* xp = (const float4*)(Vb + c * NP + sg * 160);
    float a0 = 0.f, a1 = 0.f;
    #pragma unroll 8
    for (int q = 0; q < 40; q += 2) {
        float4 u0 = up[q], x0 = xp[q];
        a0 = fmaf(u0.x, x0.x, a0); a0 = fmaf(u0.y, x0.y, a0);
        a0 = fmaf(u0.z, x0.z, a0); a0 = fmaf(u0.w, x0.w, a0);
        float4 u1 = up[q + 1], x1 = xp[q + 1];
        a1 = fmaf(u1.x, x1.x, a1); a1 = fmaf(u1.y, x1.y, a1);
        a1 = fmaf(u1.z, x1.z, a1); a1 = fmaf(u1.w, x1.w, a1);
    }
    Sp[t] = a0 + a1;
    __syncthreads();
    if (t < 160) Sb[t] = Sp[t] + Sp[t + 160];
    __syncthreads();
}

// ---------------- GL core: z = GL(v), full-width, Sb via broadcast reads ----------------
__device__ __forceinline__ void glcore(const float* __restrict__ v,
                                       const float* __restrict__ U,
                                       const float* __restrict__ Sb,
                                       const float* __restrict__ wo,
                                       const float* __restrict__ wf,
                                       const float* __restrict__ wt,
                                       const float* __restrict__ bt,
                                       float* __restrict__ z) {
    float o1[HID];
    #pragma unroll
    for (int h = 0; h < HID; h++) o1[h] = v[h];
    #pragma unroll
    for (int p = 0; p < 10; p++) {
        float u = U[p];
        const float4* srow = (const float4*)(Sb + p * HID);
        float4 s0 = srow[0], s1 = srow[1], s2 = srow[2], s3 = srow[3];
        o1[0]  = fmaf(-u, s0.x, o1[0]);  o1[1]  = fmaf(-u, s0.y, o1[1]);
        o1[2]  = fmaf(-u, s0.z, o1[2]);  o1[3]  = fmaf(-u, s0.w, o1[3]);
        o1[4]  = fmaf(-u, s1.x, o1[4]);  o1[5]  = fmaf(-u, s1.y, o1[5]);
        o1[6]  = fmaf(-u, s1.z, o1[6]);  o1[7]  = fmaf(-u, s1.w, o1[7]);
        o1[8]  = fmaf(-u, s2.x, o1[8]);  o1[9]  = fmaf(-u, s2.y, o1[9]);
        o1[10] = fmaf(-u, s2.z, o1[10]); o1[11] = fmaf(-u, s2.w, o1[11]);
        o1[12] = fmaf(-u, s3.x, o1[12]); o1[13] = fmaf(-u, s3.y, o1[13]);
        o1[14] = fmaf(-u, s3.z, o1[14]); o1[15] = fmaf(-u, s3.w, o1[15]);
    }
    float y[HID] = {};
    #pragma unroll
    for (int h2 = 0; h2 < HID; h2++) {
        float xv = v[h2];
        #pragma unroll
        for (int h = 0; h < HID; h++) y[h] = fmaf(xv, wo[h2 * HID + h], y[h]);
    }
    #pragma unroll
    for (int h = 0; h < HID; h++) y[h] = ftanh(y[h]);
    float y2[HID] = {};
    #pragma unroll
    for (int h2 = 0; h2 < HID; h2++) {
        float xv = y[h2];
        #pragma unroll
        for (int h = 0; h < HID; h++) y2[h] = fmaf(xv, wf[h2 * HID + h], y2[h]);
    }
    #pragma unroll
    for (int h = 0; h < HID; h++) z[h] = bt[h];
    #pragma unroll
    for (int h2 = 0; h2 < HID; h2++) {
        float vv = o1[h2] - ftanh(y2[h2]);
        #pragma unroll
        for (int h = 0; h < HID; h++) z[h] = fmaf(vv, wt[h2 * HID + h], z[h]);
    }
}

// ---------------- kernel 1: init + cheb + 10x GL + cstep; writes s00/s11/step1 into out ----------------
__global__ __launch_bounds__(320, 3) void k_gl(
    const float* __restrict__ flow, const float* __restrict__ Ut,
    const float* __restrict__ cheb_w, const float* __restrict__ cheb_b,
    const float* __restrict__ cou_w,
    const float* __restrict__ gl_wo, const float* __restrict__ gl_wf,
    const float* __restrict__ gl_wt, const float* __restrict__ gl_bt,
    const float* __restrict__ c_w, const float* __restrict__ c_b,
    const float* __restrict__ c1_w, const float* __restrict__ c1_b,
    float* __restrict__ out) {
    __shared__ __align__(16) float Ub[10 * NP];
    __shared__ __align__(16) float Vb[HID * NP];
    __shared__ __align__(16) float Sp[320];
    __shared__ __align__(16) float Sb[10 * HID];
    const int t = threadIdx.x, b = blockIdx.x;
    const bool act = t < N;

    for (int i = t; i < 10 * NP; i += 320) Ub[i] = Ut[i];
    for (int i = t; i < HID * NP; i += 320) Vb[i] = 0.f;   // pad stays 0 forever
    __syncthreads();
    for (int i = t; i < N * CIN; i += 320) {
        int nn = i / CIN, c = i - nn * CIN;
        Vb[c * NP + nn] = flow[(size_t)b * N * CIN + i];
    }
    __syncthreads();

    float U[10], prev2[HID], cur[HID], tk0[CIN], tk1[CIN];
    if (act) {
        #pragma unroll
        for (int p = 0; p < 10; p++) U[p] = Ub[p * NP + t];
        float xv[CIN];
        #pragma unroll
        for (int c = 0; c < CIN; c++) { xv[c] = Vb[c * NP + t]; tk0[c] = xv[c]; }
        #pragma unroll
        for (int h = 0; h < HID; h++) {
            float s = 0.f, s2 = cheb_b[h];
            #pragma unroll
            for (int c = 0; c < CIN; c++) {
                s = fmaf(xv[c], cou_w[c * HID + h], s);
                s2 = fmaf(xv[c], cheb_w[c * HID + h], s2);   // k=0: T0@x = x
            }
            prev2[h] = s;
            cur[h] = s2;
        }
    }
    reduce5(Ub, Vb, Sp, Sb, t);
    if (act) {
        #pragma unroll
        for (int c = 0; c < CIN; c++) {
            float s = tk0[c];
            #pragma unroll
            for (int p = 0; p < 10; p++) s = fmaf(-U[p], Sb[p * CIN + c], s);
            tk1[c] = s;
        }
        #pragma unroll
        for (int c = 0; c < CIN; c++) {
            float v = tk1[c];
            #pragma unroll
            for (int h = 0; h < HID; h++)
                cur[h] = fmaf(v, cheb_w[CIN * HID + c * HID + h], cur[h]);
        }
    }
    for (int k = 2; k < KORD; k++) {
        if (act) {
            #pragma unroll
            for (int c = 0; c < CIN; c++) Vb[c * NP + t] = tk1[c];
        }
        __syncthreads();
        reduce5(Ub, Vb, Sp, Sb, t);
        if (act) {
            #pragma unroll
            for (int c = 0; c < CIN; c++) {
                float lt = tk1[c];
                #pragma unroll
                for (int p = 0; p < 10; p++) lt = fmaf(-U[p], Sb[p * CIN + c], lt);
                float tn = 2.f * lt - tk0[c];
                tk0[c] = tk1[c];
                tk1[c] = tn;
            }
            #pragma unroll
            for (int c = 0; c < CIN; c++) {
                float v = tk1[c];
                #pragma unroll
                for (int h = 0; h < HID; h++)
                    cur[h] = fmaf(v, cheb_w[(k * CIN + c) * HID + h], cur[h]);
            }
        }
    }

    // ---- GL chain: 10 iters x 2 evals; 3 barriers per eval ----
    for (int it = 0; it < 10; it++) {
        if (act) {
            #pragma unroll
            for (int h = 0; h < HID; h++) Vb[h * NP + t] = cur[h];
        }
        __syncthreads();
        reduce16(Ub, Vb, Sp, Sb, t);
        float tt[HID], wv[HID];
        if (act) {
            glcore(cur, U, Sb, gl_wo, gl_wf, gl_wt, gl_bt, tt);
            #pragma unroll
            for (int h = 0; h < HID; h++) wv[h] = fmaf(2.f, tt[h], prev2[h]);
            #pragma unroll
            for (int h = 0; h < HID; h++) Vb[h * NP + t] = wv[h];
        }
        __syncthreads();
        reduce16(Ub, Vb, Sp, Sb, t);
        if (act) {
            float uu[HID];
            glcore(wv, U, Sb, gl_wo, gl_wf, gl_wt, gl_bt, uu);
            #pragma unroll
            for (int h = 0; h < HID; h++) {
                float nc = cur[h] + 0.5f * (tt[h] + uu[h]);
                prev2[h] = cur[h];
                cur[h] = nc;
            }
        }
    }

    // ---- cstep; stash s00/s11/step1 in out slots 0/1/2 (k_nl overwrites) ----
    if (act) {
        float s00[HID], s11[HID];
        #pragma unroll
        for (int h = 0; h < HID; h++) { s00[h] = c_b[h]; s11[h] = c1_b[h]; }
        #pragma unroll
        for (int h2 = 0; h2 < HID; h2++) {
            float a = prev2[h2], c2v = cur[h2];
            #pragma unroll
            for (int h = 0; h < HID; h++) {
                s00[h] = fmaf(a, c_w[h2 * HID + h], s00[h]);
                s11[h] = fmaf(c2v, c1_w[h2 * HID + h], s11[h]);
            }
        }
        float* ob = out + (size_t)(b * N + t) * 160;
        float4* wq = (float4*)ob;
        wq[0] = make_float4(s00[0], s00[1], s00[2], s00[3]);
        wq[1] = make_float4(s00[4], s00[5], s00[6], s00[7]);
        wq[2] = make_float4(s00[8], s00[9], s00[10], s00[11]);
        wq[3] = make_float4(s00[12], s00[13], s00[14], s00[15]);
        wq[4] = make_float4(s11[0], s11[1], s11[2], s11[3]);
        wq[5] = make_float4(s11[4], s11[5], s11[6], s11[7]);
        wq[6] = make_float4(s11[8], s11[9], s11[10], s11[11]);
        wq[7] = make_float4(s11[12], s11[13], s11[14], s11[15]);
        wq[8] = make_float4(cur[0], cur[1], cur[2], cur[3]);
        wq[9] = make_float4(cur[4], cur[5], cur[6], cur[7]);
        wq[10] = make_float4(cur[8], cur[9], cur[10], cur[11]);
        wq[11] = make_float4(cur[12], cur[13], cur[14], cur[15]);
    }
}

// ---------------- NL dual-eval: two independent chains share one weight stream ----------------
__device__ __forceinline__ void nl_eval2(const float* __restrict__ xA,
                                         const float* __restrict__ xB,
                                         const float* __restrict__ WiT,
                                         const float* __restrict__ WgT,
                                         const float* __restrict__ WoT,
                                         const float* __restrict__ w2,
                                         const float* __restrict__ bS,
                                         float* __restrict__ oA,
                                         float* __restrict__ oB) {
    #pragma unroll
    for (int h = 0; h < HID; h++) { oA[h] = 0.f; oB[h] = 0.f; }
    #pragma unroll 2
    for (int j = 0; j < LH; j++) {
        float bi = bS[j], bg = bS[2 * LH + j], bo = bS[3 * LH + j];
        float giA = bi, ggA = bg, goA = bo;
        float giB = bi, ggB = bg, goB = bo;
        const float4* wi = (const float4*)(WiT + j * HID);
        const float4* wg = (const float4*)(WgT + j * HID);
        const float4* wo4 = (const float4*)(WoT + j * HID);
        #pragma unroll
        for (int q = 0; q < 4; q++) {
            float4 a = wi[q], bb = wg[q], cc = wo4[q];
            float xa0 = xA[4*q+0], xa1 = xA[4*q+1], xa2 = xA[4*q+2], xa3 = xA[4*q+3];
            float xb0 = xB[4*q+0], xb1 = xB[4*q+1], xb2 = xB[4*q+2], xb3 = xB[4*q+3];
            giA = fmaf(xa0, a.x, giA); giA = fmaf(xa1, a.y, giA);
            giA = fmaf(xa2, a.z, giA); giA = fmaf(xa3, a.w, giA);
            giB = fmaf(xb0, a.x, giB); giB = fmaf(xb1, a.y, giB);
            giB = fmaf(xb2, a.z, giB); giB = fmaf(xb3, a.w, giB);
            ggA = fmaf(xa0, bb.x, ggA); ggA = fmaf(xa1, bb.y, ggA);
            ggA = fmaf(xa2, bb.z, ggA); ggA = fmaf(xa3, bb.w, ggA);
            ggB = fmaf(xb0, bb.x, ggB); ggB = fmaf(xb1, bb.y, ggB);
            ggB = fmaf(xb2, bb.z, ggB); ggB = fmaf(xb3, bb.w, ggB);
            goA = fmaf(xa0, cc.x, goA); goA = fmaf(xa1, cc.y, goA);
            goA = fmaf(xa2, cc.z, goA); goA = fmaf(xa3, cc.w, goA);
            goB = fmaf(xb0, cc.x, goB); goB = fmaf(xb1, cc.y, goB);
            goB = fmaf(xb2, cc.z, goB); goB = fmaf(xb3, cc.w, goB);
        }
        float cA = sigmoidf(giA) * ftanh(ggA);
        float cB = sigmoidf(giB) * ftanh(ggB);
        float hA = sigmoidf(goA) * ftanh(cA);
        float hB = sigmoidf(goB) * ftanh(cB);
        float thA = ftanh(hA);
        float thB = ftanh(hB);
        const float4* w2r = (const float4*)(w2 + j * HID);
        #pragma unroll
        for (int q = 0; q < 4; q++) {
            float4 a = w2r[q];
            oA[4*q+0] = fmaf(thA, a.x, oA[4*q+0]); oA[4*q+1] = fmaf(thA, a.y, oA[4*q+1]);
            oA[4*q+2] = fmaf(thA, a.z, oA[4*q+2]); oA[4*q+3] = fmaf(thA, a.w, oA[4*q+3]);
            oB[4*q+0] = fmaf(thB, a.x, oB[4*q+0]); oB[4*q+1] = fmaf(thB, a.y, oB[4*q+1]);
            oB[4*q+2] = fmaf(thB, a.z, oB[4*q+2]); oB[4*q+3] = fmaf(thB, a.w, oB[4*q+3]);
        }
    }
}

__device__ __forceinline__ void load_state(const float* __restrict__ ob,
                                           float* __restrict__ s00,
                                           float* __restrict__ s11,
                                           float* __restrict__ curf) {
    const float4* rq = (const float4*)ob;
    float4 a0 = rq[0], a1 = rq[1], a2 = rq[2], a3 = rq[3];
    float4 b0 = rq[4], b1 = rq[5], b2 = rq[6], b3 = rq[7];
    float4 c0 = rq[8], c1 = rq[9], c2 = rq[10], c3 = rq[11];
    s00[0] = a0.x; s00[1] = a0.y; s00[2] = a0.z; s00[3] = a0.w;
    s00[4] = a1.x; s00[5] = a1.y; s00[6] = a1.z; s00[7] = a1.w;
    s00[8] = a2.x; s00[9] = a2.y; s00[10] = a2.z; s00[11] = a2.w;
    s00[12] = a3.x; s00[13] = a3.y; s00[14] = a3.z; s00[15] = a3.w;
    s11[0] = b0.x; s11[1] = b0.y; s11[2] = b0.z; s11[3] = b0.w;
    s11[4] = b1.x; s11[5] = b1.y; s11[6] = b1.z; s11[7] = b1.w;
    s11[8] = b2.x; s11[9] = b2.y; s11[10] = b2.z; s11[11] = b2.w;
    s11[12] = b3.x; s11[13] = b3.y; s11[14] = b3.z; s11[15] = b3.w;
    curf[0] = c0.x; curf[1] = c0.y; curf[2] = c0.z; curf[3] = c0.w;
    curf[4] = c1.x; curf[5] = c1.y; curf[6] = c1.z; curf[7] = c1.w;
    curf[8] = c2.x; curf[9] = c2.y; curf[10] = c2.z; curf[11] = c2.w;
    curf[12] = c3.x; curf[13] = c3.y; curf[14] = c3.z; curf[15] = c3.w;
}

__device__ __forceinline__ void store_g(float* __restrict__ ob, const float* __restrict__ g) {
    float4* wq = (float4*)ob;
    wq[0] = make_float4(g[0], g[1], g[2], g[3]);
    wq[1] = make_float4(g[4], g[5], g[6], g[7]);
    wq[2] = make_float4(g[8], g[9], g[10], g[11]);
    wq[3] = make_float4(g[12], g[13], g[14], g[15]);
}

// ---------------- kernel 2: NL chain, 2 items per thread (ILP); no LDS, no barriers ----------------
__global__ __launch_bounds__(128, 2) void k_nl(
    const float* __restrict__ WiT, const float* __restrict__ WgT,
    const float* __restrict__ WoT, const float* __restrict__ bih,
    const float* __restrict__ w2, float* __restrict__ out) {
    const int gid = blockIdx.x * 128 + threadIdx.x;   // 614*128 == NH exactly
    float* obA = out + (size_t)gid * 160;
    float* obB = out + (size_t)(gid + NH) * 160;

    float s00A[HID], s11A[HID], gA[HID], p2A[HID];
    float s00B[HID], s11B[HID], gB[HID], p2B[HID];
    float ttA[HID], uuA[HID], ttB[HID], uuB[HID];
    {
        float curA[HID], curB[HID];
        load_state(obA, s00A, s11A, curA);
        load_state(obB, s00B, s11B, curB);
        nl_eval2(s11A, s11B, WiT, WgT, WoT, w2, bih, ttA, ttB);
        #pragma unroll
        for (int h = 0; h < HID; h++) {
            s00A[h] = fmaf(2.f, ttA[h], s00A[h]);
            s00B[h] = fmaf(2.f, ttB[h], s00B[h]);
        }
        nl_eval2(s00A, s00B, WiT, WgT, WoT, w2, bih, uuA, uuB);
        #pragma unroll
        for (int h = 0; h < HID; h++) {
            gA[h] = curA[h] + 0.5f * (ttA[h] + uuA[h]);
            gB[h] = curB[h] + 0.5f * (ttB[h] + uuB[h]);
            p2A[h] = s11A[h];
            p2B[h] = s11B[h];
        }
    }
    store_g(obA, gA);
    store_g(obB, gB);
    for (int i = 1; i < 10; i++) {
        nl_eval2(gA, gB, WiT, WgT, WoT, w2, bih, ttA, ttB);
        #pragma unroll
        for (int h = 0; h < HID; h++) {
            p2A[h] = fmaf(2.f, ttA[h], p2A[h]);   // p2 := tmp
            p2B[h] = fmaf(2.f, ttB[h], p2B[h]);
        }
        nl_eval2(p2A, p2B, WiT, WgT, WoT, w2, bih, uuA, uuB);
        #pragma unroll
        for (int h = 0; h < HID; h++) {
            float ngA = gA[h] + 0.5f * (ttA[h] + uuA[h]);
            float ngB = gB[h] + 0.5f * (ttB[h] + uuB[h]);
            p2A[h] = gA[h]; gA[h] = ngA;
            p2B[h] = gB[h]; gB[h] = ngB;
        }
        store_g(obA + i * HID, gA);
        store_g(obB + i * HID, gB);
    }
}

extern "C" void kernel_launch(void* const* d_in, const int* in_sizes, int n_in,
                              void* d_out, int out_size, void* d_ws, size_t ws_size,
                              hipStream_t stream) {
    const float* flow   = (const float*)d_in[0];
    const float* emb    = (const float*)d_in[1];
    const float* cheb_w = (const float*)d_in[2];
    const float* cheb_b = (const float*)d_in[3];
    const float* cou_w  = (const float*)d_in[4];
    const float* gl_out = (const float*)d_in[5];
    const float* gl_fk  = (const float*)d_in[6];
    const float* gl_tzw = (const float*)d_in[7];
    const float* gl_tzb = (const float*)d_in[8];
    const float* Wih    = (const float*)d_in[9];
    const float* lb     = (const float*)d_in[10];
    const float* w2     = (const float*)d_in[11];
    const float* c_w    = (const float*)d_in[12];
    const float* c_b    = (const float*)d_in[13];
    const float* c1_w   = (const float*)d_in[14];
    const float* c1_b   = (const float*)d_in[15];
    float* out = (float*)d_out;
    float* ws  = (float*)d_ws;

    float* Ut  = ws;            // 10*324 = 3240 floats (zero-padded)
    float* WiT = ws + 3264;
    float* WgT = WiT + 512;
    float* WoT = WgT + 512;

    k_setup<<<1, 320, 0, stream>>>(emb, Wih, Ut, WiT, WgT, WoT);
    k_gl<<<BATCH, 320, 0, stream>>>(flow, Ut, cheb_w, cheb_b, cou_w,
                                    gl_out, gl_fk, gl_tzw, gl_tzb,
                                    c_w, c_b, c1_w, c1_b, out);
    k_nl<<<NH / 128, 128, 0, stream>>>(WiT, WgT, WoT, lb, w2, out);
}

// Round 10
// 815.533 us; speedup vs baseline: 9.7529x; 1.3085x over previous
//
#include <hip/hip_runtime.h>

#define N 307
#define CIN 5
#define HID 16
#define KORD 6
#define LH 32
#define BATCH 512
#define NP 324          // padded node stride, float4-aligned; zero-padded tail
#define NITEM (BATCH * N)   // 157184 = 1228 * 128 exactly
#define NLB 1228
#define XS 17           // LDS exchange stride (odd -> 2-way max bank aliasing, free)

__device__ __forceinline__ float sigmoidf(float x) {
    return __fdividef(1.f, 1.f + __expf(-x));
}
__device__ __forceinline__ float ftanh(float x) {
    float e = __expf(2.f * x);
    return 1.f - __fdividef(2.f, e + 1.f);
}

// ---------------- setup: U^T [10][NP] (L = I - U U^T), zero-padded; LSTM transposes ----------------
__global__ __launch_bounds__(320) void k_setup(const float* __restrict__ E,
                                               const float* __restrict__ Wih,
                                               float* __restrict__ Ut,
                                               float* __restrict__ WiT,
                                               float* __restrict__ WgT,
                                               float* __restrict__ WoT) {
    __shared__ float EnS[N * 10];
    __shared__ float sS[10];
    __shared__ float dS[N];
    const int t = threadIdx.x;
    if (t < N) {
        float v[10]; float nrm = 0.f;
        #pragma unroll
        for (int p = 0; p < 10; p++) { v[p] = E[t * 10 + p]; nrm = fmaf(v[p], v[p], nrm); }
        float r = rsqrtf(nrm);
        #pragma unroll
        for (int p = 0; p < 10; p++) EnS[t * 10 + p] = v[p] * r;
    }
    __syncthreads();
    if (t < 10) {
        float s = 0.f;
        for (int nn = 0; nn < N; nn++) s += EnS[nn * 10 + t];
        sS[t] = s;
    }
    __syncthreads();
    if (t < N) {
        float dot = 0.f;
        #pragma unroll
        for (int p = 0; p < 10; p++) dot = fmaf(EnS[t * 10 + p], sS[p], dot);
        dS[t] = rsqrtf(dot);
    }
    __syncthreads();
    for (int i = t; i < 10 * NP; i += 320) {
        int p = i / NP, nn = i - p * NP;
        Ut[i] = (nn < N) ? dS[nn] * EnS[nn * 10 + p] : 0.f;
    }
    for (int i = t; i < LH * HID; i += 320) {
        int j = i >> 4, h = i & 15;
        WiT[i] = Wih[h * 4 * LH + j];
        WgT[i] = Wih[h * 4 * LH + 2 * LH + j];
        WoT[i] = Wih[h * 4 * LH + 3 * LH + j];
    }
}

// ---------------- S[p*5+c] = sum_n U[n,p]*X[n,c]; 6 segments of 52 ----------------
__device__ __forceinline__ void reduce5(const float* __restrict__ Ub,
                                        const float* __restrict__ Xb,
                                        float* __restrict__ Sp,
                                        float* __restrict__ Sb, int t) {
    const int o = t % 50, sg = t / 50;
    if (sg < 6) {
        const int p = o / 5, c = o - (o / 5) * 5;
        int n0 = sg * 52, n1 = n0 + 52; if (n1 > N) n1 = N;
        const float* up = Ub + p * NP;
        const float* xp = Xb + c * NP;
        float acc = 0.f;
        #pragma unroll 4
        for (int nn = n0; nn < n1; nn++) acc = fmaf(up[nn], xp[nn], acc);
        Sp[t] = acc;
    }
    __syncthreads();
    if (t < 50) {
        float s = 0.f;
        #pragma unroll
        for (int sgi = 0; sgi < 6; sgi++) s += Sp[t + 50 * sgi];
        Sb[t] = s;
    }
    __syncthreads();
}

// ---------------- S[p*16+h] = sum_n U[n,p]*V[n,h]; float4, 2 segments of 160 ----------------
__device__ __forceinline__ void reduce16(const float* __restrict__ Ub,
                                         const float* __restrict__ Vb,
                                         float* __restrict__ Sp,
                                         float* __restrict__ Sb, int t) {
    const int o = t % 160, sg = t / 160;     // sg in {0,1}
    const int p = o >> 4, c = o & 15;
    const float4* up = (const float4*)(Ub + p * NP + sg * 160);
    const float4* xp = (const float4*)(Vb + c * NP + sg * 160);
    float a0 = 0.f, a1 = 0.f;
    #pragma unroll 8
    for (int q = 0; q < 40; q += 2) {
        float4 u0 = up[q], x0 = xp[q];
        a0 = fmaf(u0.x, x0.x, a0); a0 = fmaf(u0.y, x0.y, a0);
        a0 = fmaf(u0.z, x0.z, a0); a0 = fmaf(u0.w, x0.w, a0);
        float4 u1 = up[q + 1], x1 = xp[q + 1];
        a1 = fmaf(u1.x, x1.x, a1); a1 = fmaf(u1.y, x1.y, a1);
        a1 = fmaf(u1.z, x1.z, a1); a1 = fmaf(u1.w, x1.w, a1);
    }
    Sp[t] = a0 + a1;
    __syncthreads();
    if (t < 160) Sb[t] = Sp[t] + Sp[t + 160];
    __syncthreads();
}

// ---------------- GL core: z = GL(v), full-width, Sb via broadcast reads ----------------
__device__ __forceinline__ void glcore(const float* __restrict__ v,
                                       const float* __restrict__ U,
                                       const float* __restrict__ Sb,
                                       const float* __restrict__ wo,
                                       const float* __restrict__ wf,
                                       const float* __restrict__ wt,
                                       const float* __restrict__ bt,
                                       float* __restrict__ z) {
    float o1[HID];
    #pragma unroll
    for (int h = 0; h < HID; h++) o1[h] = v[h];
    #pragma unroll
    for (int p = 0; p < 10; p++) {
        float u = U[p];
        const float4* srow = (const float4*)(Sb + p * HID);
        float4 s0 = srow[0], s1 = srow[1], s2 = srow[2], s3 = srow[3];
        o1[0]  = fmaf(-u, s0.x, o1[0]);  o1[1]  = fmaf(-u, s0.y, o1[1]);
        o1[2]  = fmaf(-u, s0.z, o1[2]);  o1[3]  = fmaf(-u, s0.w, o1[3]);
        o1[4]  = fmaf(-u, s1.x, o1[4]);  o1[5]  = fmaf(-u, s1.y, o1[5]);
        o1[6]  = fmaf(-u, s1.z, o1[6]);  o1[7]  = fmaf(-u, s1.w, o1[7]);
        o1[8]  = fmaf(-u, s2.x, o1[8]);  o1[9]  = fmaf(-u, s2.y, o1[9]);
        o1[10] = fmaf(-u, s2.z, o1[10]); o1[11] = fmaf(-u, s2.w, o1[11]);
        o1[12] = fmaf(-u, s3.x, o1[12]); o1[13] = fmaf(-u, s3.y, o1[13]);
        o1[14] = fmaf(-u, s3.z, o1[14]); o1[15] = fmaf(-u, s3.w, o1[15]);
    }
    float y[HID] = {};
    #pragma unroll
    for (int h2 = 0; h2 < HID; h2++) {
        float xv = v[h2];
        #pragma unroll
        for (int h = 0; h < HID; h++) y[h] = fmaf(xv, wo[h2 * HID + h], y[h]);
    }
    #pragma unroll
    for (int h = 0; h < HID; h++) y[h] = ftanh(y[h]);
    float y2[HID] = {};
    #pragma unroll
    for (int h2 = 0; h2 < HID; h2++) {
        float xv = y[h2];
        #pragma unroll
        for (int h = 0; h < HID; h++) y2[h] = fmaf(xv, wf[h2 * HID + h], y2[h]);
    }
    #pragma unroll
    for (int h = 0; h < HID; h++) z[h] = bt[h];
    #pragma unroll
    for (int h2 = 0; h2 < HID; h2++) {
        float vv = o1[h2] - ftanh(y2[h2]);
        #pragma unroll
        for (int h = 0; h < HID; h++) z[h] = fmaf(vv, wt[h2 * HID + h], z[h]);
    }
}

// ---------------- kernel 1: init + cheb + 10x GL + cstep; writes s00/s11/step1 into out ----------------
__global__ __launch_bounds__(320, 3) void k_gl(
    const float* __restrict__ flow, const float* __restrict__ Ut,
    const float* __restrict__ cheb_w, const float* __restrict__ cheb_b,
    const float* __restrict__ cou_w,
    const float* __restrict__ gl_wo, const float* __restrict__ gl_wf,
    const float* __restrict__ gl_wt, const float* __restrict__ gl_bt,
    const float* __restrict__ c_w, const float* __restrict__ c_b,
    const float* __restrict__ c1_w, const float* __restrict__ c1_b,
    float* __restrict__ out) {
    __shared__ __align__(16) float Ub[10 * NP];
    __shared__ __align__(16) float Vb[HID * NP];
    __shared__ __align__(16) float Sp[320];
    __shared__ __align__(16) float Sb[10 * HID];
    const int t = threadIdx.x, b = blockIdx.x;
    const bool act = t < N;

    for (int i = t; i < 10 * NP; i += 320) Ub[i] = Ut[i];
    for (int i = t; i < HID * NP; i += 320) Vb[i] = 0.f;   // pad stays 0 forever
    __syncthreads();
    for (int i = t; i < N * CIN; i += 320) {
        int nn = i / CIN, c = i - nn * CIN;
        Vb[c * NP + nn] = flow[(size_t)b * N * CIN + i];
    }
    __syncthreads();

    float U[10], prev2[HID], cur[HID], tk0[CIN], tk1[CIN];
    if (act) {
        #pragma unroll
        for (int p = 0; p < 10; p++) U[p] = Ub[p * NP + t];
        float xv[CIN];
        #pragma unroll
        for (int c = 0; c < CIN; c++) { xv[c] = Vb[c * NP + t]; tk0[c] = xv[c]; }
        #pragma unroll
        for (int h = 0; h < HID; h++) {
            float s = 0.f, s2 = cheb_b[h];
            #pragma unroll
            for (int c = 0; c < CIN; c++) {
                s = fmaf(xv[c], cou_w[c * HID + h], s);
                s2 = fmaf(xv[c], cheb_w[c * HID + h], s2);   // k=0: T0@x = x
            }
            prev2[h] = s;
            cur[h] = s2;
        }
    }
    reduce5(Ub, Vb, Sp, Sb, t);
    if (act) {
        #pragma unroll
        for (int c = 0; c < CIN; c++) {
            float s = tk0[c];
            #pragma unroll
            for (int p = 0; p < 10; p++) s = fmaf(-U[p], Sb[p * CIN + c], s);
            tk1[c] = s;
        }
        #pragma unroll
        for (int c = 0; c < CIN; c++) {
            float v = tk1[c];
            #pragma unroll
            for (int h = 0; h < HID; h++)
                cur[h] = fmaf(v, cheb_w[CIN * HID + c * HID + h], cur[h]);
        }
    }
    for (int k = 2; k < KORD; k++) {
        if (act) {
            #pragma unroll
            for (int c = 0; c < CIN; c++) Vb[c * NP + t] = tk1[c];
        }
        __syncthreads();
        reduce5(Ub, Vb, Sp, Sb, t);
        if (act) {
            #pragma unroll
            for (int c = 0; c < CIN; c++) {
                float lt = tk1[c];
                #pragma unroll
                for (int p = 0; p < 10; p++) lt = fmaf(-U[p], Sb[p * CIN + c], lt);
                float tn = 2.f * lt - tk0[c];
                tk0[c] = tk1[c];
                tk1[c] = tn;
            }
            #pragma unroll
            for (int c = 0; c < CIN; c++) {
                float v = tk1[c];
                #pragma unroll
                for (int h = 0; h < HID; h++)
                    cur[h] = fmaf(v, cheb_w[(k * CIN + c) * HID + h], cur[h]);
            }
        }
    }

    // ---- GL chain: 10 iters x 2 evals; 3 barriers per eval ----
    for (int it = 0; it < 10; it++) {
        if (act) {
            #pragma unroll
            for (int h = 0; h < HID; h++) Vb[h * NP + t] = cur[h];
        }
        __syncthreads();
        reduce16(Ub, Vb, Sp, Sb, t);
        float tt[HID], wv[HID];
        if (act) {
            glcore(cur, U, Sb, gl_wo, gl_wf, gl_wt, gl_bt, tt);
            #pragma unroll
            for (int h = 0; h < HID; h++) wv[h] = fmaf(2.f, tt[h], prev2[h]);
            #pragma unroll
            for (int h = 0; h < HID; h++) Vb[h * NP + t] = wv[h];
        }
        __syncthreads();
        reduce16(Ub, Vb, Sp, Sb, t);
        if (act) {
            float uu[HID];
            glcore(wv, U, Sb, gl_wo, gl_wf, gl_wt, gl_bt, uu);
            #pragma unroll
            for (int h = 0; h < HID; h++) {
                float nc = cur[h] + 0.5f * (tt[h] + uu[h]);
                prev2[h] = cur[h];
                cur[h] = nc;
            }
        }
    }

    // ---- cstep; stash s00/s11/step1 in out slots 0/1/2 (k_nl overwrites) ----
    if (act) {
        float s00[HID], s11[HID];
        #pragma unroll
        for (int h = 0; h < HID; h++) { s00[h] = c_b[h]; s11[h] = c1_b[h]; }
        #pragma unroll
        for (int h2 = 0; h2 < HID; h2++) {
            float a = prev2[h2], c2v = cur[h2];
            #pragma unroll
            for (int h = 0; h < HID; h++) {
                s00[h] = fmaf(a, c_w[h2 * HID + h], s00[h]);
                s11[h] = fmaf(c2v, c1_w[h2 * HID + h], s11[h]);
            }
        }
        float* ob = out + (size_t)(b * N + t) * 160;
        float4* wq = (float4*)ob;
        wq[0] = make_float4(s00[0], s00[1], s00[2], s00[3]);
        wq[1] = make_float4(s00[4], s00[5], s00[6], s00[7]);
        wq[2] = make_float4(s00[8], s00[9], s00[10], s00[11]);
        wq[3] = make_float4(s00[12], s00[13], s00[14], s00[15]);
        wq[4] = make_float4(s11[0], s11[1], s11[2], s11[3]);
        wq[5] = make_float4(s11[4], s11[5], s11[6], s11[7]);
        wq[6] = make_float4(s11[8], s11[9], s11[10], s11[11]);
        wq[7] = make_float4(s11[12], s11[13], s11[14], s11[15]);
        wq[8] = make_float4(cur[0], cur[1], cur[2], cur[3]);
        wq[9] = make_float4(cur[4], cur[5], cur[6], cur[7]);
        wq[10] = make_float4(cur[8], cur[9], cur[10], cur[11]);
        wq[11] = make_float4(cur[12], cur[13], cur[14], cur[15]);
    }
}

// ---------------- NL half-eval: 16 of 32 LSTM rows; j0 is SGPR (readfirstlane) so weights
// stay on the s_load/K$ path; LDS exchange; both halves get the bit-identical full sum ----------------
__device__ __forceinline__ void nl_eval_h(const float* __restrict__ x, int j0,
                                          const float* __restrict__ WiT,
                                          const float* __restrict__ WgT,
                                          const float* __restrict__ WoT,
                                          const float* __restrict__ w2,
                                          const float* __restrict__ bih,
                                          float* __restrict__ Xs,
                                          int slot, int half,
                                          float* __restrict__ outv) {
    float part[HID];
    #pragma unroll
    for (int h = 0; h < HID; h++) part[h] = 0.f;
    #pragma unroll 2
    for (int jj = 0; jj < 16; jj++) {
        const int j = j0 + jj;
        float gi = bih[j], gg = bih[2 * LH + j], go = bih[3 * LH + j];
        const float4* wi = (const float4*)(WiT + j * HID);
        const float4* wg = (const float4*)(WgT + j * HID);
        const float4* wo4 = (const float4*)(WoT + j * HID);
        #pragma unroll
        for (int q = 0; q < 4; q++) {
            float4 a = wi[q], bb = wg[q], cc = wo4[q];
            gi = fmaf(x[4 * q + 0], a.x, gi); gi = fmaf(x[4 * q + 1], a.y, gi);
            gi = fmaf(x[4 * q + 2], a.z, gi); gi = fmaf(x[4 * q + 3], a.w, gi);
            gg = fmaf(x[4 * q + 0], bb.x, gg); gg = fmaf(x[4 * q + 1], bb.y, gg);
            gg = fmaf(x[4 * q + 2], bb.z, gg); gg = fmaf(x[4 * q + 3], bb.w, gg);
            go = fmaf(x[4 * q + 0], cc.x, go); go = fmaf(x[4 * q + 1], cc.y, go);
            go = fmaf(x[4 * q + 2], cc.z, go); go = fmaf(x[4 * q + 3], cc.w, go);
        }
        float c = sigmoidf(gi) * ftanh(gg);
        float hh = sigmoidf(go) * ftanh(c);
        float th = ftanh(hh);
        const float4* w2r = (const float4*)(w2 + j * HID);
        #pragma unroll
        for (int q = 0; q < 4; q++) {
            float4 a = w2r[q];
            part[4 * q + 0] = fmaf(th, a.x, part[4 * q + 0]);
            part[4 * q + 1] = fmaf(th, a.y, part[4 * q + 1]);
            part[4 * q + 2] = fmaf(th, a.z, part[4 * q + 2]);
            part[4 * q + 3] = fmaf(th, a.w, part[4 * q + 3]);
        }
    }
    // exchange: write own partial, read both regions in canonical order
    float* my = Xs + half * (128 * XS) + slot * XS;
    #pragma unroll
    for (int h = 0; h < HID; h++) my[h] = part[h];
    __syncthreads();
    const float* r0 = Xs + slot * XS;
    const float* r1 = Xs + 128 * XS + slot * XS;
    #pragma unroll
    for (int h = 0; h < HID; h++) outv[h] = r0[h] + r1[h];
    __syncthreads();   // guard: all reads done before next eval overwrites
}

// ---------------- kernel 2: NL chain; 2 wave-groups per 128 items, row-split ----------------
__global__ __launch_bounds__(256, 3) void k_nl(
    const float* __restrict__ WiT, const float* __restrict__ WgT,
    const float* __restrict__ WoT, const float* __restrict__ bih,
    const float* __restrict__ w2, float* __restrict__ out) {
    __shared__ float Xs[2 * 128 * XS];   // 17408 B
    const int t = threadIdx.x;
    const int half = t >> 7;             // waves 0-1: rows 0-15; waves 2-3: rows 16-31
    const int slot = t & 127;
    const int item = blockIdx.x * 128 + slot;   // 1228*128 == NITEM exactly
    // (t>>7) is constant within a wave; readfirstlane makes that PROVABLE so the
    // weight/bias addresses stay wave-uniform -> s_load/K$ path (round-8 lost this).
    const int j0 = __builtin_amdgcn_readfirstlane(half * 16);
    float* ob = out + (size_t)item * 160;

    float s00[HID], s11[HID], curf[HID];
    {
        const float4* rq = (const float4*)ob;
        float4 a0 = rq[0], a1 = rq[1], a2 = rq[2], a3 = rq[3];
        float4 b0 = rq[4], b1 = rq[5], b2 = rq[6], b3 = rq[7];
        float4 c0 = rq[8], c1 = rq[9], c2 = rq[10], c3 = rq[11];
        s00[0] = a0.x; s00[1] = a0.y; s00[2] = a0.z; s00[3] = a0.w;
        s00[4] = a1.x; s00[5] = a1.y; s00[6] = a1.z; s00[7] = a1.w;
        s00[8] = a2.x; s00[9] = a2.y; s00[10] = a2.z; s00[11] = a2.w;
        s00[12] = a3.x; s00[13] = a3.y; s00[14] = a3.z; s00[15] = a3.w;
        s11[0] = b0.x; s11[1] = b0.y; s11[2] = b0.z; s11[3] = b0.w;
        s11[4] = b1.x; s11[5] = b1.y; s11[6] = b1.z; s11[7] = b1.w;
        s11[8] = b2.x; s11[9] = b2.y; s11[10] = b2.z; s11[11] = b2.w;
        s11[12] = b3.x; s11[13] = b3.y; s11[14] = b3.z; s11[15] = b3.w;
        curf[0] = c0.x; curf[1] = c0.y; curf[2] = c0.z; curf[3] = c0.w;
        curf[4] = c1.x; curf[5] = c1.y; curf[6] = c1.z; curf[7] = c1.w;
        curf[8] = c2.x; curf[9] = c2.y; curf[10] = c2.z; curf[11] = c2.w;
        curf[12] = c3.x; curf[13] = c3.y; curf[14] = c3.z; curf[15] = c3.w;
    }

    float tt[HID], uu[HID], g[HID], p2[HID];
    nl_eval_h(s11, j0, WiT, WgT, WoT, w2, bih, Xs, slot, half, tt);
    #pragma unroll
    for (int h = 0; h < HID; h++) s00[h] = fmaf(2.f, tt[h], s00[h]);
    nl_eval_h(s00, j0, WiT, WgT, WoT, w2, bih, Xs, slot, half, uu);
    #pragma unroll
    for (int h = 0; h < HID; h++) {
        g[h] = curf[h] + 0.5f * (tt[h] + uu[h]);
        p2[h] = s11[h];
    }
    if (half == 0) {
        float4* wq = (float4*)ob;
        wq[0] = make_float4(g[0], g[1], g[2], g[3]);
        wq[1] = make_float4(g[4], g[5], g[6], g[7]);
        wq[2] = make_float4(g[8], g[9], g[10], g[11]);
        wq[3] = make_float4(g[12], g[13], g[14], g[15]);
    }
    for (int i = 1; i < 10; i++) {
        nl_eval_h(g, j0, WiT, WgT, WoT, w2, bih, Xs, slot, half, tt);
        #pragma unroll
        for (int h = 0; h < HID; h++) p2[h] = fmaf(2.f, tt[h], p2[h]);   // p2 := tmp
        nl_eval_h(p2, j0, WiT, WgT, WoT, w2, bih, Xs, slot, half, uu);
        #pragma unroll
        for (int h = 0; h < HID; h++) {
            float ng = g[h] + 0.5f * (tt[h] + uu[h]);
            p2[h] = g[h];
            g[h] = ng;
        }
        if (half == 0) {
            float4* wq = (float4*)(ob + i * HID);
            wq[0] = make_float4(g[0], g[1], g[2], g[3]);
            wq[1] = make_float4(g[4], g[5], g[6], g[7]);
            wq[2] = make_float4(g[8], g[9], g[10], g[11]);
            wq[3] = make_float4(g[12], g[13], g[14], g[15]);
        }
    }
}

extern "C" void kernel_launch(void* const* d_in, const int* in_sizes, int n_in,
                              void* d_out, int out_size, void* d_ws, size_t ws_size,
                              hipStream_t stream) {
    const float* flow   = (const float*)d_in[0];
    const float* emb    = (const float*)d_in[1];
    const float* cheb_w = (const float*)d_in[2];
    const float* cheb_b = (const float*)d_in[3];
    const float* cou_w  = (const float*)d_in[4];
    const float* gl_out = (const float*)d_in[5];
    const float* gl_fk  = (const float*)d_in[6];
    const float* gl_tzw = (const float*)d_in[7];
    const float* gl_tzb = (const float*)d_in[8];
    const float* Wih    = (const float*)d_in[9];
    const float* lb     = (const float*)d_in[10];
    const float* w2     = (const float*)d_in[11];
    const float* c_w    = (const float*)d_in[12];
    const float* c_b    = (const float*)d_in[13];
    const float* c1_w   = (const float*)d_in[14];
    const float* c1_b   = (const float*)d_in[15];
    float* out = (float*)d_out;
    float* ws  = (float*)d_ws;

    float* Ut  = ws;            // 10*324 = 3240 floats (zero-padded)
    float* WiT = ws + 3264;
    float* WgT = WiT + 512;
    float* WoT = WgT + 512;

    k_setup<<<1, 320, 0, stream>>>(emb, Wih, Ut, WiT, WgT, WoT);
    k_gl<<<BATCH, 320, 0, stream>>>(flow, Ut, cheb_w, cheb_b, cou_w,
                                    gl_out, gl_fk, gl_tzw, gl_tzb,
                                    c_w, c_b, c1_w, c1_b, out);
    k_nl<<<NLB, 256, 0, stream>>>(WiT, WgT, WoT, lb, w2, out);
}